// Round 1
// baseline (57129.901 us; speedup 1.0000x reference)
//
#include <hip/hip_runtime.h>
#include <hip/hip_cooperative_groups.h>

namespace cg = cooperative_groups;

#define BB   64      // batch
#define TT   256     // timesteps
#define II   512     // input dim
#define HH   1024    // hidden dim
#define KCB  512     // codebook entries
#define GH   4096    // 4*H

__device__ __forceinline__ float sigf(float x) { return 1.0f / (1.0f + expf(-x)); }

// ws layout (floats):
//   [0 .. HH*BB)        hT buffer 0   (h transposed: [col][row])
//   [HH*BB .. 2*HH*BB)  hT buffer 1
//   [2*HH*BB .. +BB*KCB) dist^2 [row][k]
__global__ __launch_bounds__(256, 1)
void lstm_vq(const float* __restrict__ seq,   // [B][T][I]
             const int*   __restrict__ nit,   // [B]
             const float* __restrict__ Wx,    // [I][4H]
             const float* __restrict__ Wh,    // [H][4H]
             const float* __restrict__ bias,  // [4H]
             const float* __restrict__ cb,    // [K][H]
             float* __restrict__ out,         // [64 idx][64*1024 quant][64*1024 unquant]
             float* __restrict__ ws)
{
    cg::grid_group grid = cg::this_grid();
    __shared__ float lds[256 * 64];
    __shared__ int sBest;

    const int tid = threadIdx.x;
    const int r   = tid & 63;        // batch row (lane)
    const int jw  = tid >> 6;        // wave id 0..3 -> column within block
    // wave-uniform h-column this thread owns
    const int jcol = __builtin_amdgcn_readfirstlane((int)blockIdx.x * 4 + jw);

    float* hT0  = ws;
    float* hT1  = ws + HH * BB;
    float* dist = ws + 2 * HH * BB;
    float* qz   = out + BB;              // quantized section
    float* uq   = out + BB + BB * HH;    // unquantized section

    const int myN = nit[r];
    int maxN = 0;
    for (int i = 0; i < BB; ++i) maxN = max(maxN, nit[i]);

    const float* WxBase = Wx + jcol;     // uniform (SGPR) base pointers
    const float* WhBase = Wh + jcol;

    float c = 0.0f;

    for (int t = 0; t <= maxN; ++t) {
        const float* hprev = (t & 1) ? hT1 : hT0;
        float*       hnext = (t & 1) ? hT0 : hT1;

        float a0 = bias[jcol];
        float a1 = bias[HH + jcol];
        float a2 = bias[2 * HH + jcol];
        float a3 = bias[3 * HH + jcol];

        // ---------- x contribution: 2 chunks of 256 along I ----------
        for (int c0 = 0; c0 < II; c0 += 256) {
            __syncthreads();
            // transpose-stage x_t chunk into LDS, XOR-swizzled (conflict-free)
            {
                const float* src = seq + (size_t)t * II + c0;  // + row*T*I + kk
                #pragma unroll 4
                for (int pass = 0; pass < 64; ++pass) {        // pass = batch row
                    float v = src[(size_t)pass * (TT * II) + tid];   // kk = tid, coalesced
                    lds[(tid << 6) | (pass ^ (tid & 31))] = v;
                }
            }
            __syncthreads();
            const float* wb = WxBase + (size_t)c0 * GH;
            #pragma unroll 8
            for (int k = 0; k < 256; ++k) {
                float v = lds[(k << 6) | (r ^ (k & 31))];
                const float* w = wb + (size_t)k * GH;   // uniform -> s_load
                a0 = fmaf(v, w[0],      a0);
                a1 = fmaf(v, w[HH],     a1);
                a2 = fmaf(v, w[2 * HH], a2);
                a3 = fmaf(v, w[3 * HH], a3);
            }
        }

        // ---------- h contribution: 4 chunks of 256 along H ----------
        if (t > 0) {
            for (int c0 = 0; c0 < HH; c0 += 256) {
                __syncthreads();
                {   // plain contiguous copy (hT already [col][row]) via float4
                    const float4* s4 = (const float4*)(hprev + (size_t)c0 * BB);
                    float4* l4 = (float4*)lds;
                    #pragma unroll 4
                    for (int i = tid; i < 256 * 64 / 4; i += 256) l4[i] = s4[i];
                }
                __syncthreads();
                const float* wb = WhBase + (size_t)c0 * GH;
                #pragma unroll 8
                for (int k = 0; k < 256; ++k) {
                    float v = lds[(k << 6) | r];
                    const float* w = wb + (size_t)k * GH;   // uniform -> s_load
                    a0 = fmaf(v, w[0],      a0);
                    a1 = fmaf(v, w[HH],     a1);
                    a2 = fmaf(v, w[2 * HH], a2);
                    a3 = fmaf(v, w[3 * HH], a3);
                }
            }
        }

        // ---------- gates ----------
        float iv = sigf(a0);
        float fv = sigf(a1);
        float gv = tanhf(a2);
        float ov = sigf(a3);
        c = fv * c + iv * gv;
        float h = ov * tanhf(c);

        hnext[(size_t)jcol * BB + r] = h;          // coalesced over lanes r
        if (t == myN) uq[(size_t)r * HH + jcol] = h;

        __threadfence();
        grid.sync();
    }

    // ---------- VQ: distance^2 matrix [64][512] ----------
    {
        const int wid  = (int)blockIdx.x * 4 + jw;   // 0..1023
        const int lane = r;
        for (int p = wid * 32; p < wid * 32 + 32; ++p) {
            int rr = p >> 9;        // 0..63
            int kk = p & 511;       // 0..511
            const float4* u4 = (const float4*)(uq + (size_t)rr * HH);
            const float4* c4 = (const float4*)(cb + (size_t)kk * HH);
            float s = 0.0f;
            #pragma unroll
            for (int q = 0; q < 4; ++q) {
                float4 a = u4[lane + q * 64];
                float4 b = c4[lane + q * 64];
                float dx = a.x - b.x, dy = a.y - b.y;
                float dz = a.z - b.z, dw = a.w - b.w;
                s += dx * dx + dy * dy + dz * dz + dw * dw;
            }
            #pragma unroll
            for (int off = 32; off > 0; off >>= 1) s += __shfl_xor(s, off, 64);
            if (lane == 0) dist[(size_t)rr * KCB + kk] = s;
        }
        __threadfence();
    }
    grid.sync();

    // ---------- argmin + emit outputs (blocks 0..63, one row each) ----------
    if (blockIdx.x < BB) {
        const int rr = blockIdx.x;
        if (tid < 64) {
            float best = 3.4e38f;
            int   bi   = 0;
            for (int kk = tid; kk < KCB; kk += 64) {
                float v = dist[(size_t)rr * KCB + kk];
                if (v < best) { best = v; bi = kk; }   // strict < keeps first occurrence
            }
            #pragma unroll
            for (int off = 32; off > 0; off >>= 1) {
                float ovv = __shfl_xor(best, off, 64);
                int   oii = __shfl_xor(bi,   off, 64);
                if (ovv < best || (ovv == best && oii < bi)) { best = ovv; bi = oii; }
            }
            if (tid == 0) { sBest = bi; out[rr] = (float)bi; }
        }
        __syncthreads();
        const int bk = sBest;
        const float4* c4 = (const float4*)(cb + (size_t)bk * HH);
        float4*       q4 = (float4*)(qz + (size_t)rr * HH);
        for (int d = tid; d < HH / 4; d += 256) q4[d] = c4[d];
    }
}

extern "C" void kernel_launch(void* const* d_in, const int* in_sizes, int n_in,
                              void* d_out, int out_size, void* d_ws, size_t ws_size,
                              hipStream_t stream) {
    const float* seq  = (const float*)d_in[0];
    const int*   nit  = (const int*)  d_in[1];
    const float* Wx   = (const float*)d_in[2];
    const float* Wh   = (const float*)d_in[3];
    const float* bias = (const float*)d_in[4];
    const float* cb   = (const float*)d_in[5];
    float* out = (float*)d_out;
    float* ws  = (float*)d_ws;

    void* args[] = { &seq, &nit, &Wx, &Wh, &bias, &cb, &out, &ws };
    hipLaunchCooperativeKernel((void*)lstm_vq, dim3(256), dim3(256), args, 0, stream);
}

// Round 2
// 29503.104 us; speedup vs baseline: 1.9364x; 1.9364x over previous
//
#include <hip/hip_runtime.h>
#include <hip/hip_cooperative_groups.h>

namespace cg = cooperative_groups;

#define BB   64      // batch
#define TT   256     // timesteps
#define II   512     // input dim
#define HH   1024    // hidden dim
#define KCB  512     // codebook entries
#define GH   4096    // 4*H
#define KTOT 1536    // II + HH
#define PAD  65      // LDS row stride (floats), conflict-free

// ws layout (floats):
//   [0 .. 64K)        hT buffer 0   ([jcol][r])
//   [64K .. 128K)     hT buffer 1
//   [128K .. 160K)    dist^2 [r][k]
//   [160K .. +6.29M)  WT  (transposed weights [4096][1536]) when use_wt
#define WS_HT0   0
#define WS_HT1   (HH*BB)
#define WS_DIST  (2*HH*BB)
#define WS_WT    (2*HH*BB + BB*KCB)
#define WS_NEED_BYTES ((size_t)(WS_WT + (size_t)GH*KTOT) * 4)

__device__ __forceinline__ float sigf(float x) { return 1.0f / (1.0f + expf(-x)); }

__global__ __launch_bounds__(256, 1)
void lstm_vq(const float* __restrict__ seq,   // [B][T][I]
             const int*   __restrict__ nit,   // [B]
             const float* __restrict__ Wx,    // [I][4H]
             const float* __restrict__ Wh,    // [H][4H]
             const float* __restrict__ bias,  // [4H]
             const float* __restrict__ cb,    // [K][H]
             float* __restrict__ out,         // [64 idx][64*1024 quant][64*1024 unquant]
             float* __restrict__ ws,
             int use_wt)
{
    cg::grid_group grid = cg::this_grid();
    __shared__ float lds_a[256 * PAD];   // 66560 B staging / transpose tile
    __shared__ float ex[16 * BB];        // gate exchange
    __shared__ int sBest;

    const int tid = threadIdx.x;
    const int r   = tid & 63;                                  // batch row (lane)
    const int jwS = __builtin_amdgcn_readfirstlane(tid >> 6);  // wave id = gate id
    const int bid = (int)blockIdx.x;
    // XCD-contiguous column ownership: XCD (bid%8) covers jcols [128*xcd, 128*xcd+128)
    const int jbase = __builtin_amdgcn_readfirstlane((bid & 7) * 128 + (bid >> 3) * 4);

    float* hT0  = ws + WS_HT0;
    float* hT1  = ws + WS_HT1;
    float* dist = ws + WS_DIST;
    float* WT   = ws + WS_WT;
    float* qz   = out + BB;              // quantized section
    float* uq   = out + BB + BB * HH;    // unquantized section

    // ---------------- one-time: build WT[col][k] = W[k][col] ----------------
    if (use_wt) {
        const int c0 = bid * 16;                         // 16 cols per block
        for (int kt = 0; kt < KTOT; kt += 64) {
            __syncthreads();
            #pragma unroll
            for (int i = 0; i < 4; ++i) {
                int ky = i * 16 + (tid >> 4);            // 0..63
                int cx = tid & 15;
                int kk = kt + ky;
                float v = (kk < II) ? Wx[(size_t)kk * GH + c0 + cx]
                                    : Wh[(size_t)(kk - II) * GH + c0 + cx];
                lds_a[cx * PAD + ky] = v;
            }
            __syncthreads();
            {
                int cx = tid >> 4;                       // 0..15
                int k4 = (tid & 15) * 4;                 // 0..60
                float4 v = *(float4*)&lds_a[cx * PAD + k4];
                *(float4*)&WT[(size_t)(c0 + cx) * KTOT + kt + k4] = v;
            }
        }
        grid.sync();
    }

    const int myN = nit[r];
    int maxN = 0;
    for (int i = 0; i < BB; ++i) maxN = max(maxN, nit[i]);

    // wave-uniform weight bases: wave jw computes gate jw for cols jbase..jbase+3
    const float* wtbase = WT + (size_t)(jwS * HH + jbase) * KTOT;  // + jc*KTOT + k
    const float* wxbase = Wx + jwS * HH + jbase;                   // + k*GH + jc
    const float* whbase = Wh + jwS * HH + jbase;

    float c = 0.0f;

    for (int t = 0; t <= maxN; ++t) {
        const float* hprev = (t & 1) ? hT1 : hT0;
        float*       hnext = (t & 1) ? hT0 : hT1;

        float a0 = bias[jwS * HH + jbase + 0];
        float a1 = bias[jwS * HH + jbase + 1];
        float a2 = bias[jwS * HH + jbase + 2];
        float a3 = bias[jwS * HH + jbase + 3];

        const int nchunks = (t == 0) ? 2 : 6;   // h==0 at t==0: x chunks only
        for (int kc = 0; kc < nchunks; ++kc) {
            __syncthreads();
            if (kc < 2) {
                // ---- stage x chunk: transpose [r][k] -> lds[k][r], pad-65 ----
                const float* src = seq + (size_t)t * II + kc * 256;   // + r*T*I + k
                #pragma unroll 8
                for (int pass = 0; pass < 64; ++pass) {
                    float v = src[(size_t)pass * (TT * II) + tid];    // k = tid, coalesced
                    lds_a[tid * PAD + pass] = v;
                }
            } else {
                // ---- stage h chunk: ws hT already [k][r]; contiguous copy ----
                const float4* s4 = (const float4*)(hprev + (size_t)(kc - 2) * 256 * BB);
                #pragma unroll
                for (int i = tid; i < 256 * 64 / 4; i += 256) {
                    int k  = i >> 4;
                    int r4 = (i & 15) * 4;
                    float4 v = s4[i];
                    *(float4*)&lds_a[k * PAD + r4] = v;
                }
            }
            __syncthreads();

            // ---- GEMM over this chunk: acc[jc] += A[r][k] * WT[col_jc][k] ----
            const float* la = lds_a + r;
            if (use_wt) {
                const float* w = wtbase + kc * 256;
                #pragma unroll 8
                for (int k = 0; k < 256; ++k) {
                    float v = la[k * PAD];
                    a0 = fmaf(v, w[k],            a0);
                    a1 = fmaf(v, w[KTOT + k],     a1);
                    a2 = fmaf(v, w[2 * KTOT + k], a2);
                    a3 = fmaf(v, w[3 * KTOT + k], a3);
                }
            } else {
                const float* w = (kc < 2) ? (wxbase + (size_t)kc * 256 * GH)
                                          : (whbase + (size_t)(kc - 2) * 256 * GH);
                #pragma unroll 8
                for (int k = 0; k < 256; ++k) {
                    float v = la[k * PAD];
                    const float* wk = w + (size_t)k * GH;   // 4 consecutive cols
                    a0 = fmaf(v, wk[0], a0);
                    a1 = fmaf(v, wk[1], a1);
                    a2 = fmaf(v, wk[2], a2);
                    a3 = fmaf(v, wk[3], a3);
                }
            }
        }

        // ---- exchange: wave jw has gate jw for cols 0..3 -> regroup by col ----
        __syncthreads();
        ex[(jwS * 4 + 0) * BB + r] = a0;
        ex[(jwS * 4 + 1) * BB + r] = a1;
        ex[(jwS * 4 + 2) * BB + r] = a2;
        ex[(jwS * 4 + 3) * BB + r] = a3;
        __syncthreads();
        // this thread owns (r, jcol = jbase + jwS)
        float za = ex[(0 * 4 + jwS) * BB + r];
        float zf = ex[(1 * 4 + jwS) * BB + r];
        float zg = ex[(2 * 4 + jwS) * BB + r];
        float zo = ex[(3 * 4 + jwS) * BB + r];

        float iv = sigf(za);
        float fv = sigf(zf);
        float gv = tanhf(zg);
        float ov = sigf(zo);
        c = fv * c + iv * gv;
        float h = ov * tanhf(c);

        hnext[(size_t)(jbase + jwS) * BB + r] = h;     // coalesced over lanes r
        if (t == myN) uq[(size_t)r * HH + jbase + jwS] = h;

        __threadfence();
        grid.sync();
    }

    // ---------- VQ: distance^2 matrix [64][512] ----------
    {
        const int wid  = bid * 4 + jwS;   // 0..1023
        const int lane = r;
        for (int p = wid * 32; p < wid * 32 + 32; ++p) {
            int rr = p >> 9;        // 0..63
            int kk = p & 511;       // 0..511
            const float4* u4 = (const float4*)(uq + (size_t)rr * HH);
            const float4* c4 = (const float4*)(cb + (size_t)kk * HH);
            float s = 0.0f;
            #pragma unroll
            for (int q = 0; q < 4; ++q) {
                float4 a = u4[lane + q * 64];
                float4 b = c4[lane + q * 64];
                float dx = a.x - b.x, dy = a.y - b.y;
                float dz = a.z - b.z, dw = a.w - b.w;
                s += dx * dx + dy * dy + dz * dz + dw * dw;
            }
            #pragma unroll
            for (int off = 32; off > 0; off >>= 1) s += __shfl_xor(s, off, 64);
            if (lane == 0) dist[(size_t)rr * KCB + kk] = s;
        }
        __threadfence();
    }
    grid.sync();

    // ---------- argmin + emit outputs (blocks 0..63, one row each) ----------
    if (bid < BB) {
        const int rr = bid;
        if (tid < 64) {
            float best = 3.4e38f;
            int   bi   = 0;
            for (int kk = tid; kk < KCB; kk += 64) {
                float v = dist[(size_t)rr * KCB + kk];
                if (v < best) { best = v; bi = kk; }   // strict < keeps first occurrence
            }
            #pragma unroll
            for (int off = 32; off > 0; off >>= 1) {
                float ovv = __shfl_xor(best, off, 64);
                int   oii = __shfl_xor(bi,   off, 64);
                if (ovv < best || (ovv == best && oii < bi)) { best = ovv; bi = oii; }
            }
            if (tid == 0) { sBest = bi; out[rr] = (float)bi; }
        }
        __syncthreads();
        const int bk = sBest;
        const float4* c4 = (const float4*)(cb + (size_t)bk * HH);
        float4*       q4 = (float4*)(qz + (size_t)rr * HH);
        for (int d = tid; d < HH / 4; d += 256) q4[d] = c4[d];
    }
}

extern "C" void kernel_launch(void* const* d_in, const int* in_sizes, int n_in,
                              void* d_out, int out_size, void* d_ws, size_t ws_size,
                              hipStream_t stream) {
    const float* seq  = (const float*)d_in[0];
    const int*   nit  = (const int*)  d_in[1];
    const float* Wx   = (const float*)d_in[2];
    const float* Wh   = (const float*)d_in[3];
    const float* bias = (const float*)d_in[4];
    const float* cb   = (const float*)d_in[5];
    float* out = (float*)d_out;
    float* ws  = (float*)d_ws;
    int use_wt = (ws_size >= WS_NEED_BYTES) ? 1 : 0;

    void* args[] = { &seq, &nit, &Wx, &Wh, &bias, &cb, &out, &ws, &use_wt };
    hipLaunchCooperativeKernel((void*)lstm_vq, dim3(256), dim3(256), args, 0, stream);
}

// Round 4
// 20524.963 us; speedup vs baseline: 2.7834x; 1.4374x over previous
//
#include <hip/hip_runtime.h>
#include <hip/hip_cooperative_groups.h>

namespace cg = cooperative_groups;

typedef unsigned short u16;
typedef unsigned int   u32;
typedef __attribute__((ext_vector_type(8))) short short8;
typedef __attribute__((ext_vector_type(4))) float f32x4;

#define BB   64
#define TT   256
#define II   512
#define HH   1024
#define KCB  512
#define GH   4096
#define KTOT 1536

#define APAD 136    // u16 elems per A-tile row (128 + 8) -> 272 B stride
#define BPAD 1544   // u16 elems per B row (1536 + 8) -> 3088 B stride

// ws layout (float units):
//   [0 .. 6291456)            WT: transposed weights [4096 zcol][1536 k] f32
//   [6291456 .. +131072)      h planes: 2 x [64][1024] f32
//   [6422528 .. +32768)       dist^2 [64][512]
#define WS_WT   0
#define WS_H    (GH*KTOT)
#define WS_DIST (WS_H + 2*HH*BB)

__device__ __forceinline__ float sigf(float x){ return 1.0f/(1.0f+expf(-x)); }
__device__ __forceinline__ u16 bf16r(float f){ u32 u = __float_as_uint(f); u += 0x7FFFu + ((u>>16)&1u); return (u16)(u>>16); }
__device__ __forceinline__ float bf16f(u16 h){ return __uint_as_float(((u32)h)<<16); }

__global__ __launch_bounds__(256, 1)
void lstm_vq(const float* __restrict__ seq, const int* __restrict__ nit,
             const float* __restrict__ Wx, const float* __restrict__ Wh,
             const float* __restrict__ bias, const float* __restrict__ cb,
             float* __restrict__ out, float* __restrict__ ws)
{
    cg::grid_group grid = cg::this_grid();
    __shared__ __align__(16) u16 aHi[64*APAD];   // 17408 B
    __shared__ __align__(16) u16 aLo[64*APAD];   // 17408 B
    __shared__ __align__(16) u16 bHi[16*BPAD];   // 49408 B
    __shared__ __align__(16) u16 bLo[16*BPAD];   // 49408 B
    __shared__ float ex[BB*16];                  // 4096 B
    __shared__ int sBest;

    const int tid = threadIdx.x;
    const int l   = tid & 63;
    const int w   = tid >> 6;
    const int bid = (int)blockIdx.x;

    float* WT   = ws + WS_WT;
    float* hpl  = ws + WS_H;
    float* dist = ws + WS_DIST;
    float* qz   = out + BB;
    float* uq   = out + BB + BB*HH;

    // ---------------- one-time: WT[zcol][k] = W[k][zcol] (round-2-proven) ----------------
    {
        const int c0 = bid * 16;
        float* tile = (float*)aHi;               // 16 x 68 f32 scratch (4352 B)
        for (int kt = 0; kt < KTOT; kt += 64) {
            __syncthreads();
            #pragma unroll
            for (int ii2 = 0; ii2 < 4; ++ii2) {
                int ky = ii2*16 + (tid>>4);
                int cx = tid & 15;
                int kk = kt + ky;
                float v = (kk < II) ? Wx[(size_t)kk*GH + c0 + cx]
                                    : Wh[(size_t)(kk-II)*GH + c0 + cx];
                tile[cx*68 + ky] = v;
            }
            __syncthreads();
            {
                int cx = tid >> 4;
                int k4 = (tid & 15) * 4;
                f32x4 v = *(f32x4*)&tile[cx*68 + k4];
                *(f32x4*)&WT[(size_t)(c0+cx)*KTOT + kt + k4] = v;
            }
        }
        grid.sync();
    }

    // ---------------- one-time: split this block's 16 z-cols into bHi/bLo (LDS) ----------------
    {
        __syncthreads();
        const int n  = tid >> 4;                              // 0..15 = MFMA col
        const int zc = ((n>>2)<<10) + (bid<<2) + (n&3);       // gate*1024 + bid*4 + cc
        const float* wr = WT + (size_t)zc*KTOT;
        for (int k = (tid&15)*8; k < KTOT; k += 128) {
            f32x4 v0 = *(const f32x4*)(wr + k);
            f32x4 v1 = *(const f32x4*)(wr + k + 4);
            short8 ph, pl;
            #pragma unroll
            for (int e = 0; e < 8; ++e) {
                float fv = (e<4) ? v0[e] : v1[e-4];
                u16 hb = bf16r(fv);
                ph[e] = (short)hb;
                pl[e] = (short)bf16r(fv - bf16f(hb));
            }
            *(short8*)&bHi[n*BPAD + k] = ph;
            *(short8*)&bLo[n*BPAD + k] = pl;
        }
        __syncthreads();
    }

    // ---------------- per-thread roles ----------------
    const int rEx  = tid >> 2;
    const int ccEx = tid & 3;
    const int hcol = (bid<<2) + ccEx;
    const int myN  = nit[rEx];
    int maxN = 0;
    for (int i = 0; i < BB; ++i) maxN = max(maxN, nit[i]);

    const float bi_ = bias[hcol], bf_ = bias[HH+hcol], bg_ = bias[2*HH+hcol], bo_ = bias[3*HH+hcol];

    const int arow = (w<<4) + (l&15);        // A row this lane reads
    const int ag   = (l>>4)<<3;              // 8-elem k-group offset
    const int bn   = l & 15;                 // B col this lane reads

    const int srow = tid >> 2;               // staging: batch row
    const int seg  = (tid & 3) << 5;         // staging: 32-elem k segment

    float cst = 0.0f;

    for (int t = 0; t <= maxN; ++t) {
        const float* hprev = hpl + (size_t)(t&1)*(HH*BB);
        float*       hnext = hpl + (size_t)(1-(t&1))*(HH*BB);
        const int nch = (t == 0) ? 4 : 12;

        f32x4 acc0 = {0.f,0.f,0.f,0.f};
        f32x4 acc1 = {0.f,0.f,0.f,0.f};
        f32x4 acc2 = {0.f,0.f,0.f,0.f};

        for (int c = 0; c < nch; ++c) {
            // load 32 k-elems (f32) for (srow, seg) of chunk c
            const float* src = (c < 4)
                ? (seq + (size_t)srow*(TT*II) + (size_t)t*II + (c<<7) + seg)
                : (hprev + (size_t)srow*HH + ((c-4)<<7) + seg);
            f32x4 vr[8];
            #pragma unroll
            for (int j = 0; j < 8; ++j) vr[j] = ((const f32x4*)src)[j];

            __syncthreads();     // all reads of previous A tile complete
            #pragma unroll
            for (int q = 0; q < 4; ++q) {
                short8 ph, pl;
                #pragma unroll
                for (int e = 0; e < 8; ++e) {
                    float fv = (e<4) ? vr[2*q][e] : vr[2*q+1][e-4];
                    u16 hb = bf16r(fv);
                    ph[e] = (short)hb;
                    pl[e] = (short)bf16r(fv - bf16f(hb));
                }
                *(short8*)&aHi[srow*APAD + seg + q*8] = ph;
                *(short8*)&aLo[srow*APAD + seg + q*8] = pl;
            }
            __syncthreads();     // tile staged

            #pragma unroll
            for (int ks = 0; ks < 4; ++ks) {
                int ao = arow*APAD + (ks<<5) + ag;
                int bo = bn*BPAD + (c<<7) + (ks<<5) + ag;
                short8 ah  = *(const short8*)&aHi[ao];
                short8 al  = *(const short8*)&aLo[ao];
                short8 bhv = *(const short8*)&bHi[bo];
                short8 blv = *(const short8*)&bLo[bo];
                acc0 = __builtin_amdgcn_mfma_f32_16x16x32_bf16(ah, bhv, acc0, 0,0,0);
                acc1 = __builtin_amdgcn_mfma_f32_16x16x32_bf16(al, bhv, acc1, 0,0,0);
                acc2 = __builtin_amdgcn_mfma_f32_16x16x32_bf16(ah, blv, acc2, 0,0,0);
            }
        }

        // ---- exchange: D (col=l&15, row=(l>>4)*4+j) -> per-(r,hcol) thread ----
        {
            const int n  = l & 15;
            const int r0 = (w<<4) + ((l>>4)<<2);
            #pragma unroll
            for (int j = 0; j < 4; ++j)
                ex[(r0+j)*16 + n] = acc0[j] + acc1[j] + acc2[j];
        }
        __syncthreads();
        {
            float zi = ex[rEx*16 + 0*4 + ccEx] + bi_;
            float zf = ex[rEx*16 + 1*4 + ccEx] + bf_;
            float zg = ex[rEx*16 + 2*4 + ccEx] + bg_;
            float zo = ex[rEx*16 + 3*4 + ccEx] + bo_;
            float iv = sigf(zi), fv = sigf(zf), gv = tanhf(zg), ov = sigf(zo);
            cst = fv*cst + iv*gv;
            float h = ov * tanhf(cst);
            hnext[(size_t)rEx*HH + hcol] = h;
            if (t == myN) uq[(size_t)rEx*HH + hcol] = h;
        }
        __threadfence();
        grid.sync();
    }

    // ---------- VQ: distance^2 matrix [64][512] ----------
    {
        const int wid = bid*4 + w;
        for (int p = wid*32; p < wid*32 + 32; ++p) {
            int rr = p >> 9;
            int kk = p & 511;
            const f32x4* u4 = (const f32x4*)(uq + (size_t)rr*HH);
            const f32x4* c4 = (const f32x4*)(cb + (size_t)kk*HH);
            float s = 0.0f;
            #pragma unroll
            for (int q = 0; q < 4; ++q) {
                f32x4 a = u4[l + q*64];
                f32x4 b = c4[l + q*64];
                f32x4 d = a - b;
                s += d[0]*d[0] + d[1]*d[1] + d[2]*d[2] + d[3]*d[3];
            }
            #pragma unroll
            for (int off = 32; off > 0; off >>= 1) s += __shfl_xor(s, off, 64);
            if (l == 0) dist[(size_t)rr*KCB + kk] = s;
        }
        __threadfence();
    }
    grid.sync();

    // ---------- argmin + emit outputs (blocks 0..63, one row each) ----------
    if (bid < BB) {
        const int rr = bid;
        if (tid < 64) {
            float best = 3.4e38f;
            int   bi   = 0;
            for (int kk = tid; kk < KCB; kk += 64) {
                float v = dist[(size_t)rr*KCB + kk];
                if (v < best) { best = v; bi = kk; }
            }
            #pragma unroll
            for (int off = 32; off > 0; off >>= 1) {
                float ovv = __shfl_xor(best, off, 64);
                int   oii = __shfl_xor(bi,   off, 64);
                if (ovv < best || (ovv == best && oii < bi)) { best = ovv; bi = oii; }
            }
            if (tid == 0) { sBest = bi; out[rr] = (float)bi; }
        }
        __syncthreads();
        const int bk = sBest;
        const f32x4* c4 = (const f32x4*)(cb + (size_t)bk*HH);
        f32x4*       q4 = (f32x4*)(qz + (size_t)rr*HH);
        for (int d = tid; d < HH/4; d += 256) q4[d] = c4[d];
    }
}

extern "C" void kernel_launch(void* const* d_in, const int* in_sizes, int n_in,
                              void* d_out, int out_size, void* d_ws, size_t ws_size,
                              hipStream_t stream) {
    const float* seq  = (const float*)d_in[0];
    const int*   nit  = (const int*)  d_in[1];
    const float* Wx   = (const float*)d_in[2];
    const float* Wh   = (const float*)d_in[3];
    const float* bias = (const float*)d_in[4];
    const float* cb   = (const float*)d_in[5];
    float* out = (float*)d_out;
    float* ws  = (float*)d_ws;

    void* args[] = { &seq, &nit, &Wx, &Wh, &bias, &cb, &out, &ws };
    hipLaunchCooperativeKernel((void*)lstm_vq, dim3(256), dim3(256), args, 0, stream);
}

// Round 5
// 15628.549 us; speedup vs baseline: 3.6555x; 1.3133x over previous
//
#include <hip/hip_runtime.h>
#include <hip/hip_cooperative_groups.h>

namespace cg = cooperative_groups;

typedef unsigned short u16;
typedef unsigned int   u32;
typedef unsigned long long u64;
typedef __attribute__((ext_vector_type(8))) short short8;
typedef __attribute__((ext_vector_type(4))) float f32x4;

#define BB   64
#define TT   256
#define II   512
#define HH   1024
#define KCB  512
#define GH   4096
#define KTOT 1536

#define APAD 136    // u16 elems per A-tile row (272 B stride)
#define BPAD 1544   // u16 elems per B row (3088 B stride)

// ws layout (float units):
//   [0 .. 6291456)            WT: transposed weights [4096 zcol][1536 k] f32
//   [6291456 .. +131072)      h planes: 2 x [64][1024] u32 (bf16hi<<16 | bf16lo)
//   [.. +32768)               dist^2 [64][512] f32
//   [.. +64)                  barrier counter (u32, line-isolated)
#define WS_WT   0
#define WS_H    (GH*KTOT)
#define WS_DIST (WS_H + 2*HH*BB)
#define WS_CTR  (WS_DIST + BB*KCB)

#define LD_AG(p)   __hip_atomic_load((p), __ATOMIC_RELAXED, __HIP_MEMORY_SCOPE_AGENT)
#define ST_AG(p,v) __hip_atomic_store((p), (v), __ATOMIC_RELAXED, __HIP_MEMORY_SCOPE_AGENT)

__device__ __forceinline__ float sigf(float x){ return 1.0f/(1.0f+expf(-x)); }
__device__ __forceinline__ u16 bf16r(float f){ u32 u = __float_as_uint(f); u += 0x7FFFu + ((u>>16)&1u); return (u16)(u>>16); }
__device__ __forceinline__ float bf16f(u16 h){ return __uint_as_float(((u32)h)<<16); }

// release: my stores are sc1 and retired; signal arrival (one add per block)
__device__ __forceinline__ void bar_arrive(u32* ctr, int tid){
    asm volatile("s_waitcnt vmcnt(0)" ::: "memory");
    __syncthreads();
    if (tid == 0) atomicAdd(ctr, 1u);          // agent-scope, relaxed
}
// acquire: spin until all arrived; sc1 data reads after this are fresh
__device__ __forceinline__ void bar_wait(u32* ctr, int tid, u32 target){
    if (tid == 0) { while (LD_AG(ctr) < target) {} }
    __syncthreads();
}

__global__ __launch_bounds__(256, 1)
void lstm_vq(const float* __restrict__ seq, const int* __restrict__ nit,
             const float* __restrict__ Wx, const float* __restrict__ Wh,
             const float* __restrict__ bias, const float* __restrict__ cb,
             float* __restrict__ out, float* __restrict__ ws)
{
    cg::grid_group grid = cg::this_grid();
    __shared__ __align__(16) u16 aHi[64*APAD];
    __shared__ __align__(16) u16 aLo[64*APAD];
    __shared__ __align__(16) u16 bHi[16*BPAD];
    __shared__ __align__(16) u16 bLo[16*BPAD];
    __shared__ float ex[BB*16];
    __shared__ int sBest;

    const int tid = threadIdx.x;
    const int l   = tid & 63;
    const int w   = tid >> 6;
    const int bid = (int)blockIdx.x;

    float* WT   = ws + WS_WT;
    u32*   hbuf = (u32*)(ws + WS_H);
    float* dist = ws + WS_DIST;
    u32*   ctr  = (u32*)(ws + WS_CTR);
    float* qz   = out + BB;
    float* uq   = out + BB + BB*HH;

    if (bid == 0 && tid == 0) ST_AG(ctr, 0u);   // reset before the cg sync below

    // ---------------- one-time: WT[zcol][k] = W[k][zcol] ----------------
    {
        const int c0 = bid * 16;
        float* tile = (float*)aHi;
        for (int kt = 0; kt < KTOT; kt += 64) {
            __syncthreads();
            #pragma unroll
            for (int ii2 = 0; ii2 < 4; ++ii2) {
                int ky = ii2*16 + (tid>>4);
                int cx = tid & 15;
                int kk = kt + ky;
                float v = (kk < II) ? Wx[(size_t)kk*GH + c0 + cx]
                                    : Wh[(size_t)(kk-II)*GH + c0 + cx];
                tile[cx*68 + ky] = v;
            }
            __syncthreads();
            {
                int cx = tid >> 4;
                int k4 = (tid & 15) * 4;
                f32x4 v = *(f32x4*)&tile[cx*68 + k4];
                *(f32x4*)&WT[(size_t)(c0+cx)*KTOT + kt + k4] = v;
            }
        }
        grid.sync();   // full fences: WT visible; also orders ctr reset
    }

    // ---------------- one-time: split this block's 16 z-cols into bHi/bLo ----------------
    {
        __syncthreads();
        const int n  = tid >> 4;
        const int zc = ((n>>2)<<10) + (bid<<2) + (n&3);
        const float* wr = WT + (size_t)zc*KTOT;
        for (int k = (tid&15)*8; k < KTOT; k += 128) {
            f32x4 v0 = *(const f32x4*)(wr + k);
            f32x4 v1 = *(const f32x4*)(wr + k + 4);
            short8 ph, pl;
            #pragma unroll
            for (int e = 0; e < 8; ++e) {
                float fv = (e<4) ? v0[e] : v1[e-4];
                u16 hb = bf16r(fv);
                ph[e] = (short)hb;
                pl[e] = (short)bf16r(fv - bf16f(hb));
            }
            *(short8*)&bHi[n*BPAD + k] = ph;
            *(short8*)&bLo[n*BPAD + k] = pl;
        }
        __syncthreads();
    }

    // ---------------- per-thread roles ----------------
    const int rEx  = tid >> 2;
    const int ccEx = tid & 3;
    const int hcol = (bid<<2) + ccEx;
    const int myN  = nit[rEx];
    int maxN = 0;
    for (int i = 0; i < BB; ++i) maxN = max(maxN, nit[i]);

    const float bi_ = bias[hcol], bf_ = bias[HH+hcol], bg_ = bias[2*HH+hcol], bo_ = bias[3*HH+hcol];

    const int arow = (w<<4) + (l&15);
    const int ag   = (l>>4)<<3;
    const int bn   = l & 15;

    const int srow = tid >> 2;
    const int seg  = (tid & 3) << 5;

    float cst = 0.0f;
    f32x4 vr[8];    // x-phase staging regs (f32)
    u64   hv[16];   // h-phase staging regs (packed bf16 pairs)

    for (int t = 0; t <= maxN; ++t) {
        const u32* hprev = hbuf + (size_t)(t&1)*(HH*BB);
        u32*       hnext = hbuf + (size_t)(1-(t&1))*(HH*BB);

        f32x4 acc0 = {0.f,0.f,0.f,0.f};
        f32x4 acc1 = {0.f,0.f,0.f,0.f};
        f32x4 acc2 = {0.f,0.f,0.f,0.f};

        // ======== x phase (chunks 0..3) — independent of h(t-1) ========
        {
            const float* s0 = seq + (size_t)srow*(TT*II) + (size_t)t*II + seg;
            #pragma unroll
            for (int j = 0; j < 8; ++j) vr[j] = ((const f32x4*)s0)[j];
        }
        for (int c = 0; c < 4; ++c) {
            __syncthreads();
            #pragma unroll
            for (int q = 0; q < 4; ++q) {
                short8 ph, pl;
                #pragma unroll
                for (int e = 0; e < 8; ++e) {
                    float fv = (e<4) ? vr[2*q][e] : vr[2*q+1][e-4];
                    u16 hb = bf16r(fv);
                    ph[e] = (short)hb;
                    pl[e] = (short)bf16r(fv - bf16f(hb));
                }
                *(short8*)&aHi[srow*APAD + seg + q*8] = ph;
                *(short8*)&aLo[srow*APAD + seg + q*8] = pl;
            }
            if (c < 3) {
                const float* sn = seq + (size_t)srow*(TT*II) + (size_t)t*II + ((c+1)<<7) + seg;
                #pragma unroll
                for (int j = 0; j < 8; ++j) vr[j] = ((const f32x4*)sn)[j];
            }
            __syncthreads();
            #pragma unroll
            for (int ks = 0; ks < 4; ++ks) {
                int ao = arow*APAD + (ks<<5) + ag;
                int bo = bn*BPAD + (c<<7) + (ks<<5) + ag;
                short8 ah  = *(const short8*)&aHi[ao];
                short8 al  = *(const short8*)&aLo[ao];
                short8 bhv = *(const short8*)&bHi[bo];
                short8 blv = *(const short8*)&bLo[bo];
                acc0 = __builtin_amdgcn_mfma_f32_16x16x32_bf16(ah, bhv, acc0, 0,0,0);
                acc1 = __builtin_amdgcn_mfma_f32_16x16x32_bf16(al, bhv, acc1, 0,0,0);
                acc2 = __builtin_amdgcn_mfma_f32_16x16x32_bf16(ah, blv, acc2, 0,0,0);
            }
        }

        // ======== wait for h(t-1), then h phase (chunks 4..11) ========
        if (t > 0) {
            bar_wait(ctr, tid, (u32)t * 256u);
            {
                const u64* h0 = (const u64*)(hprev + (size_t)srow*HH + seg);
                #pragma unroll
                for (int j = 0; j < 16; ++j) hv[j] = LD_AG(h0 + j);
            }
            for (int c = 4; c < 12; ++c) {
                __syncthreads();
                #pragma unroll
                for (int q = 0; q < 4; ++q) {
                    short8 ph, pl;
                    #pragma unroll
                    for (int e = 0; e < 8; ++e) {
                        u32 v = (u32)(hv[q*4 + (e>>1)] >> ((e&1) ? 32 : 0));
                        ph[e] = (short)(v >> 16);
                        pl[e] = (short)(v & 0xFFFFu);
                    }
                    *(short8*)&aHi[srow*APAD + seg + q*8] = ph;
                    *(short8*)&aLo[srow*APAD + seg + q*8] = pl;
                }
                if (c < 11) {
                    const u64* hn = (const u64*)(hprev + (size_t)srow*HH + ((c-3)<<7) + seg);
                    #pragma unroll
                    for (int j = 0; j < 16; ++j) hv[j] = LD_AG(hn + j);
                }
                __syncthreads();
                #pragma unroll
                for (int ks = 0; ks < 4; ++ks) {
                    int ao = arow*APAD + (ks<<5) + ag;
                    int bo = bn*BPAD + (c<<7) + (ks<<5) + ag;
                    short8 ah  = *(const short8*)&aHi[ao];
                    short8 al  = *(const short8*)&aLo[ao];
                    short8 bhv = *(const short8*)&bHi[bo];
                    short8 blv = *(const short8*)&bLo[bo];
                    acc0 = __builtin_amdgcn_mfma_f32_16x16x32_bf16(ah, bhv, acc0, 0,0,0);
                    acc1 = __builtin_amdgcn_mfma_f32_16x16x32_bf16(al, bhv, acc1, 0,0,0);
                    acc2 = __builtin_amdgcn_mfma_f32_16x16x32_bf16(ah, blv, acc2, 0,0,0);
                }
            }
        }

        // ---- exchange: D (col=l&15, row=(l>>4)*4+j) -> per-(r,hcol) thread ----
        __syncthreads();
        {
            const int n  = l & 15;
            const int r0 = (w<<4) + ((l>>4)<<2);
            #pragma unroll
            for (int j = 0; j < 4; ++j)
                ex[(r0+j)*16 + n] = acc0[j] + acc1[j] + acc2[j];
        }
        __syncthreads();
        {
            float zi = ex[rEx*16 + 0*4 + ccEx] + bi_;
            float zf = ex[rEx*16 + 1*4 + ccEx] + bf_;
            float zg = ex[rEx*16 + 2*4 + ccEx] + bg_;
            float zo = ex[rEx*16 + 3*4 + ccEx] + bo_;
            float iv = sigf(zi), fv = sigf(zf), gv = tanhf(zg), ov = sigf(zo);
            cst = fv*cst + iv*gv;
            float h = ov * tanhf(cst);
            u16 hb = bf16r(h);
            u16 lb = bf16r(h - bf16f(hb));
            ST_AG(&hnext[(size_t)rEx*HH + hcol], ((u32)hb << 16) | (u32)lb);
            if (t == myN) ST_AG(&uq[(size_t)rEx*HH + hcol], h);
        }
        bar_arrive(ctr, tid);          // instance t+1
    }

    // ---------- VQ: distance^2 matrix [64][512] ----------
    bar_wait(ctr, tid, (u32)(maxN+1) * 256u);
    {
        const int wid = bid*4 + w;
        for (int p = wid*32; p < wid*32 + 32; ++p) {
            int rr = p >> 9;
            int kk = p & 511;
            const u64* u8p = (const u64*)(uq + (size_t)rr*HH);
            const f32x4* c4 = (const f32x4*)(cb + (size_t)kk*HH);
            float s = 0.0f;
            #pragma unroll
            for (int q = 0; q < 4; ++q) {
                u64 e0 = LD_AG(u8p + 2*(l + q*64));
                u64 e1 = LD_AG(u8p + 2*(l + q*64) + 1);
                f32x4 b = c4[l + q*64];
                float a0 = __uint_as_float((u32)e0), a1 = __uint_as_float((u32)(e0>>32));
                float a2 = __uint_as_float((u32)e1), a3 = __uint_as_float((u32)(e1>>32));
                float d0 = a0-b[0], d1 = a1-b[1], d2 = a2-b[2], d3 = a3-b[3];
                s += d0*d0 + d1*d1 + d2*d2 + d3*d3;
            }
            #pragma unroll
            for (int off = 32; off > 0; off >>= 1) s += __shfl_xor(s, off, 64);
            if (l == 0) ST_AG(&dist[(size_t)rr*KCB + kk], s);
        }
    }
    bar_arrive(ctr, tid);              // instance maxN+2
    bar_wait(ctr, tid, (u32)(maxN+2) * 256u);

    // ---------- argmin + emit outputs (blocks 0..63, one row each) ----------
    if (bid < BB) {
        const int rr = bid;
        if (tid < 64) {
            float best = 3.4e38f;
            int   bi   = 0;
            for (int kk = tid; kk < KCB; kk += 64) {
                float v = LD_AG(&dist[(size_t)rr*KCB + kk]);
                if (v < best) { best = v; bi = kk; }
            }
            #pragma unroll
            for (int off = 32; off > 0; off >>= 1) {
                float ovv = __shfl_xor(best, off, 64);
                int   oii = __shfl_xor(bi,   off, 64);
                if (ovv < best || (ovv == best && oii < bi)) { best = ovv; bi = oii; }
            }
            if (tid == 0) { sBest = bi; out[rr] = (float)bi; }
        }
        __syncthreads();
        const int bk = sBest;
        const f32x4* c4 = (const f32x4*)(cb + (size_t)bk*HH);
        f32x4*       q4 = (f32x4*)(qz + (size_t)rr*HH);
        for (int d = tid; d < HH/4; d += 256) q4[d] = c4[d];
    }
}

extern "C" void kernel_launch(void* const* d_in, const int* in_sizes, int n_in,
                              void* d_out, int out_size, void* d_ws, size_t ws_size,
                              hipStream_t stream) {
    const float* seq  = (const float*)d_in[0];
    const int*   nit  = (const int*)  d_in[1];
    const float* Wx   = (const float*)d_in[2];
    const float* Wh   = (const float*)d_in[3];
    const float* bias = (const float*)d_in[4];
    const float* cb   = (const float*)d_in[5];
    float* out = (float*)d_out;
    float* ws  = (float*)d_ws;

    void* args[] = { &seq, &nit, &Wx, &Wh, &bias, &cb, &out, &ws };
    hipLaunchCooperativeKernel((void*)lstm_vq, dim3(256), dim3(256), args, 0, stream);
}

// Round 6
// 15188.232 us; speedup vs baseline: 3.7615x; 1.0290x over previous
//
#include <hip/hip_runtime.h>
#include <hip/hip_cooperative_groups.h>

namespace cg = cooperative_groups;

typedef unsigned short u16;
typedef unsigned int   u32;
typedef unsigned long long u64;
typedef __attribute__((ext_vector_type(8))) short short8;
typedef __attribute__((ext_vector_type(4))) float f32x4;

#define BB   64
#define TT   256
#define II   512
#define HH   1024
#define KCB  512
#define GH   4096
#define KTOT 1536

#define APAD 136    // u16 elems per A-tile row (272 B stride)
#define BPAD 1544   // u16 elems per B row (3088 B stride)

// ws layout (float units):
//   [0 .. 6291456)            WT: transposed weights [4096 zcol][1536 k] f32
//   [6291456 .. +131072)      h planes: 2 x [64][1024] u32 (bf16hi<<16 | bf16lo)
//   [.. +32768)               dist^2 [64][512] f32
//   [.. +544)                 barrier: 17 lines x 32 u32 (grp[8], root, goflag[8])
#define WS_WT   0
#define WS_H    (GH*KTOT)
#define WS_DIST (WS_H + 2*HH*BB)
#define WS_BAR  (WS_DIST + BB*KCB)

#define LD_AG(p)   __hip_atomic_load((p), __ATOMIC_RELAXED, __HIP_MEMORY_SCOPE_AGENT)
#define ST_AG(p,v) __hip_atomic_store((p), (v), __ATOMIC_RELAXED, __HIP_MEMORY_SCOPE_AGENT)

__device__ __forceinline__ float sigf(float x){ return 1.0f/(1.0f+expf(-x)); }
__device__ __forceinline__ u16 bf16r(float f){ u32 u = __float_as_uint(f); u += 0x7FFFu + ((u>>16)&1u); return (u16)(u>>16); }
__device__ __forceinline__ float bf16f(u16 h){ return __uint_as_float(((u32)h)<<16); }

// hierarchical release: group add -> root add -> broadcast go-flags
__device__ __forceinline__ void bar_arrive(u32* bar, int bid, int tid, int e){
    asm volatile("s_waitcnt vmcnt(0)" ::: "memory");
    __syncthreads();
    if (tid == 0) {
        u32 old = atomicAdd(bar + (bid & 7) * 32, 1u);
        if (old == (u32)(e * 32 - 1)) {                 // last of my 32-block group
            u32 old2 = atomicAdd(bar + 8 * 32, 1u);
            if (old2 == (u32)(e * 8 - 1)) {             // last group
                #pragma unroll
                for (int gg = 0; gg < 8; ++gg)
                    ST_AG(bar + (9 + gg) * 32, (u32)e);
            }
        }
    }
}
// acquire: read-only spin (with backoff) on my group's go-flag line
__device__ __forceinline__ void bar_wait(u32* bar, int bid, int tid, int e){
    if (tid == 0) {
        while ((int)LD_AG(bar + (9 + (bid & 7)) * 32) < e)
            __builtin_amdgcn_s_sleep(1);
    }
    __syncthreads();
}

__global__ __launch_bounds__(256, 1)
void lstm_vq(const float* __restrict__ seq, const int* __restrict__ nit,
             const float* __restrict__ Wx, const float* __restrict__ Wh,
             const float* __restrict__ bias, const float* __restrict__ cb,
             float* __restrict__ out, float* __restrict__ ws)
{
    cg::grid_group grid = cg::this_grid();
    __shared__ __align__(16) u16 aHi[64*APAD];
    __shared__ __align__(16) u16 aLo[64*APAD];
    __shared__ __align__(16) u16 bHi[16*BPAD];
    __shared__ __align__(16) u16 bLo[16*BPAD];
    __shared__ float ex[BB*16];
    __shared__ int sBest;

    const int tid = threadIdx.x;
    const int l   = tid & 63;
    const int w   = tid >> 6;
    const int bid = (int)blockIdx.x;

    float* WT   = ws + WS_WT;
    u32*   hbuf = (u32*)(ws + WS_H);
    float* dist = ws + WS_DIST;
    u32*   bar  = (u32*)(ws + WS_BAR);
    float* qz   = out + BB;
    float* uq   = out + BB + BB*HH;

    if (bid == 0 && tid < 17) ST_AG(bar + tid * 32, 0u);   // reset; ordered by grid.sync below

    // ---------------- one-time: WT[zcol][k] = W[k][zcol] ----------------
    {
        const int c0 = bid * 16;
        float* tile = (float*)aHi;
        for (int kt = 0; kt < KTOT; kt += 64) {
            __syncthreads();
            #pragma unroll
            for (int ii2 = 0; ii2 < 4; ++ii2) {
                int ky = ii2*16 + (tid>>4);
                int cx = tid & 15;
                int kk = kt + ky;
                float v = (kk < II) ? Wx[(size_t)kk*GH + c0 + cx]
                                    : Wh[(size_t)(kk-II)*GH + c0 + cx];
                tile[cx*68 + ky] = v;
            }
            __syncthreads();
            {
                int cx = tid >> 4;
                int k4 = (tid & 15) * 4;
                f32x4 v = *(f32x4*)&tile[cx*68 + k4];
                *(f32x4*)&WT[(size_t)(c0+cx)*KTOT + kt + k4] = v;
            }
        }
        grid.sync();   // full fences: WT visible; orders barrier reset
    }

    // ---------------- one-time: split this block's 16 z-cols into bHi/bLo ----------------
    {
        __syncthreads();
        const int n  = tid >> 4;
        const int zc = ((n>>2)<<10) + (bid<<2) + (n&3);
        const float* wr = WT + (size_t)zc*KTOT;
        for (int k = (tid&15)*8; k < KTOT; k += 128) {
            f32x4 v0 = *(const f32x4*)(wr + k);
            f32x4 v1 = *(const f32x4*)(wr + k + 4);
            short8 ph, pl;
            #pragma unroll
            for (int e = 0; e < 8; ++e) {
                float fv = (e<4) ? v0[e] : v1[e-4];
                u16 hb = bf16r(fv);
                ph[e] = (short)hb;
                pl[e] = (short)bf16r(fv - bf16f(hb));
            }
            *(short8*)&bHi[n*BPAD + k] = ph;
            *(short8*)&bLo[n*BPAD + k] = pl;
        }
        __syncthreads();
    }

    // ---------------- per-thread roles ----------------
    const int rEx  = tid >> 2;
    const int ccEx = tid & 3;
    const int hcol = (bid<<2) + ccEx;
    const int myN  = nit[rEx];
    int maxN = 0;
    for (int i = 0; i < BB; ++i) maxN = max(maxN, nit[i]);

    const float bi_ = bias[hcol], bf_ = bias[HH+hcol], bg_ = bias[2*HH+hcol], bo_ = bias[3*HH+hcol];

    const int arow = (w<<4) + (l&15);
    const int ag   = (l>>4)<<3;
    const int bn   = l & 63 & 15;

    const int srow = tid >> 2;
    const int seg  = (tid & 3) << 5;

    float cst = 0.0f;
    f32x4 vr[8];     // x-phase staging regs (f32)
    u64 hvA[16], hvB[16];   // h-phase 2-deep prefetch regs (packed bf16 pairs)

#define HLOAD(dst, hc) { \
    const u64* hp_ = (const u64*)(hprev + (size_t)srow*HH + ((hc)<<7) + seg); \
    _Pragma("unroll") for (int j=0;j<16;++j) dst[j] = LD_AG(hp_ + j); }

#define HSTAGE(srcv) { \
    _Pragma("unroll") for (int q=0;q<4;++q){ \
        short8 ph, pl; \
        _Pragma("unroll") for (int ee=0;ee<8;++ee){ \
            u32 v = (u32)(srcv[q*4+(ee>>1)] >> ((ee&1)?32:0)); \
            ph[ee]=(short)(v>>16); pl[ee]=(short)(v&0xFFFFu); } \
        *(short8*)&aHi[srow*APAD+seg+q*8]=ph; \
        *(short8*)&aLo[srow*APAD+seg+q*8]=pl; } }

#define HMFMA(hc) { \
    _Pragma("unroll") for (int ks=0;ks<4;++ks){ \
        int ao=arow*APAD+(ks<<5)+ag; \
        int bo=bn*BPAD+(((hc)+4)<<7)+(ks<<5)+ag; \
        short8 ah=*(const short8*)&aHi[ao]; \
        short8 al=*(const short8*)&aLo[ao]; \
        short8 bhv=*(const short8*)&bHi[bo]; \
        short8 blv=*(const short8*)&bLo[bo]; \
        acc0=__builtin_amdgcn_mfma_f32_16x16x32_bf16(ah,bhv,acc0,0,0,0); \
        acc1=__builtin_amdgcn_mfma_f32_16x16x32_bf16(al,bhv,acc1,0,0,0); \
        acc2=__builtin_amdgcn_mfma_f32_16x16x32_bf16(ah,blv,acc2,0,0,0); } }

    for (int t = 0; t <= maxN; ++t) {
        const u32* hprev = hbuf + (size_t)(t&1)*(HH*BB);
        u32*       hnext = hbuf + (size_t)(1-(t&1))*(HH*BB);

        f32x4 acc0 = {0.f,0.f,0.f,0.f};
        f32x4 acc1 = {0.f,0.f,0.f,0.f};
        f32x4 acc2 = {0.f,0.f,0.f,0.f};

        // ======== x phase (chunks 0..3) — independent of h(t-1) ========
        {
            const float* s0 = seq + (size_t)srow*(TT*II) + (size_t)t*II + seg;
            #pragma unroll
            for (int j = 0; j < 8; ++j) vr[j] = ((const f32x4*)s0)[j];
        }
        for (int c = 0; c < 4; ++c) {
            __syncthreads();
            #pragma unroll
            for (int q = 0; q < 4; ++q) {
                short8 ph, pl;
                #pragma unroll
                for (int e = 0; e < 8; ++e) {
                    float fv = (e<4) ? vr[2*q][e] : vr[2*q+1][e-4];
                    u16 hb = bf16r(fv);
                    ph[e] = (short)hb;
                    pl[e] = (short)bf16r(fv - bf16f(hb));
                }
                *(short8*)&aHi[srow*APAD + seg + q*8] = ph;
                *(short8*)&aLo[srow*APAD + seg + q*8] = pl;
            }
            if (c < 3) {
                const float* sn = seq + (size_t)srow*(TT*II) + (size_t)t*II + ((c+1)<<7) + seg;
                #pragma unroll
                for (int j = 0; j < 8; ++j) vr[j] = ((const f32x4*)sn)[j];
            }
            __syncthreads();
            #pragma unroll
            for (int ks = 0; ks < 4; ++ks) {
                int ao = arow*APAD + (ks<<5) + ag;
                int bo = bn*BPAD + (c<<7) + (ks<<5) + ag;
                short8 ah  = *(const short8*)&aHi[ao];
                short8 al  = *(const short8*)&aLo[ao];
                short8 bhv = *(const short8*)&bHi[bo];
                short8 blv = *(const short8*)&bLo[bo];
                acc0 = __builtin_amdgcn_mfma_f32_16x16x32_bf16(ah, bhv, acc0, 0,0,0);
                acc1 = __builtin_amdgcn_mfma_f32_16x16x32_bf16(al, bhv, acc1, 0,0,0);
                acc2 = __builtin_amdgcn_mfma_f32_16x16x32_bf16(ah, blv, acc2, 0,0,0);
            }
        }

        // ======== wait for h(t-1), then h phase (chunks 0..7), 2-deep prefetch ========
        if (t > 0) {
            bar_wait(bar, bid, tid, t);
            HLOAD(hvA, 0); HLOAD(hvB, 1);
            __syncthreads(); HSTAGE(hvA); HLOAD(hvA, 2); __syncthreads(); HMFMA(0);
            __syncthreads(); HSTAGE(hvB); HLOAD(hvB, 3); __syncthreads(); HMFMA(1);
            __syncthreads(); HSTAGE(hvA); HLOAD(hvA, 4); __syncthreads(); HMFMA(2);
            __syncthreads(); HSTAGE(hvB); HLOAD(hvB, 5); __syncthreads(); HMFMA(3);
            __syncthreads(); HSTAGE(hvA); HLOAD(hvA, 6); __syncthreads(); HMFMA(4);
            __syncthreads(); HSTAGE(hvB); HLOAD(hvB, 7); __syncthreads(); HMFMA(5);
            __syncthreads(); HSTAGE(hvA);                __syncthreads(); HMFMA(6);
            __syncthreads(); HSTAGE(hvB);                __syncthreads(); HMFMA(7);
        }

        // ---- exchange: D (col=l&15, row=(l>>4)*4+j) -> per-(r,hcol) thread ----
        __syncthreads();
        {
            const int n  = l & 15;
            const int r0 = (w<<4) + ((l>>4)<<2);
            #pragma unroll
            for (int j = 0; j < 4; ++j)
                ex[(r0+j)*16 + n] = acc0[j] + acc1[j] + acc2[j];
        }
        __syncthreads();
        {
            float zi = ex[rEx*16 + 0*4 + ccEx] + bi_;
            float zf = ex[rEx*16 + 1*4 + ccEx] + bf_;
            float zg = ex[rEx*16 + 2*4 + ccEx] + bg_;
            float zo = ex[rEx*16 + 3*4 + ccEx] + bo_;
            float iv = sigf(zi), fv = sigf(zf), gv = tanhf(zg), ov = sigf(zo);
            cst = fv*cst + iv*gv;
            float h = ov * tanhf(cst);
            u16 hb = bf16r(h);
            u16 lb = bf16r(h - bf16f(hb));
            ST_AG(&hnext[(size_t)rEx*HH + hcol], ((u32)hb << 16) | (u32)lb);
            if (t == myN) ST_AG(&uq[(size_t)rEx*HH + hcol], h);
        }
        bar_arrive(bar, bid, tid, t + 1);
    }

    // ---------- VQ: distance^2 matrix [64][512] ----------
    bar_wait(bar, bid, tid, maxN + 1);
    {
        const int wid = bid*4 + w;
        for (int p = wid*32; p < wid*32 + 32; ++p) {
            int rr = p >> 9;
            int kk = p & 511;
            const u64* u8p = (const u64*)(uq + (size_t)rr*HH);
            const f32x4* c4 = (const f32x4*)(cb + (size_t)kk*HH);
            float s = 0.0f;
            #pragma unroll
            for (int q = 0; q < 4; ++q) {
                u64 e0 = LD_AG(u8p + 2*(l + q*64));
                u64 e1 = LD_AG(u8p + 2*(l + q*64) + 1);
                f32x4 b = c4[l + q*64];
                float a0 = __uint_as_float((u32)e0), a1 = __uint_as_float((u32)(e0>>32));
                float a2 = __uint_as_float((u32)e1), a3 = __uint_as_float((u32)(e1>>32));
                float d0 = a0-b[0], d1 = a1-b[1], d2 = a2-b[2], d3 = a3-b[3];
                s += d0*d0 + d1*d1 + d2*d2 + d3*d3;
            }
            #pragma unroll
            for (int off = 32; off > 0; off >>= 1) s += __shfl_xor(s, off, 64);
            if (l == 0) ST_AG(&dist[(size_t)rr*KCB + kk], s);
        }
    }
    bar_arrive(bar, bid, tid, maxN + 2);
    bar_wait(bar, bid, tid, maxN + 2);

    // ---------- argmin + emit outputs (blocks 0..63, one row each) ----------
    if (bid < BB) {
        const int rr = bid;
        if (tid < 64) {
            float best = 3.4e38f;
            int   bi   = 0;
            for (int kk = tid; kk < KCB; kk += 64) {
                float v = LD_AG(&dist[(size_t)rr*KCB + kk]);
                if (v < best) { best = v; bi = kk; }
            }
            #pragma unroll
            for (int off = 32; off > 0; off >>= 1) {
                float ovv = __shfl_xor(best, off, 64);
                int   oii = __shfl_xor(bi,   off, 64);
                if (ovv < best || (ovv == best && oii < bi)) { best = ovv; bi = oii; }
            }
            if (tid == 0) { sBest = bi; out[rr] = (float)bi; }
        }
        __syncthreads();
        const int bk = sBest;
        const f32x4* c4 = (const f32x4*)(cb + (size_t)bk*HH);
        f32x4*       q4 = (f32x4*)(qz + (size_t)rr*HH);
        for (int d = tid; d < HH/4; d += 256) q4[d] = c4[d];
    }
}

extern "C" void kernel_launch(void* const* d_in, const int* in_sizes, int n_in,
                              void* d_out, int out_size, void* d_ws, size_t ws_size,
                              hipStream_t stream) {
    const float* seq  = (const float*)d_in[0];
    const int*   nit  = (const int*)  d_in[1];
    const float* Wx   = (const float*)d_in[2];
    const float* Wh   = (const float*)d_in[3];
    const float* bias = (const float*)d_in[4];
    const float* cb   = (const float*)d_in[5];
    float* out = (float*)d_out;
    float* ws  = (float*)d_ws;

    void* args[] = { &seq, &nit, &Wx, &Wh, &bias, &cb, &out, &ws };
    hipLaunchCooperativeKernel((void*)lstm_vq, dim3(256), dim3(256), args, 0, stream);
}

// Round 8
// 4493.198 us; speedup vs baseline: 12.7148x; 3.3803x over previous
//
#include <hip/hip_runtime.h>
#include <hip/hip_cooperative_groups.h>

namespace cg = cooperative_groups;

typedef unsigned short u16;
typedef unsigned int   u32;
typedef unsigned long long u64;
typedef __attribute__((ext_vector_type(8))) short short8;
typedef __attribute__((ext_vector_type(4))) float f32x4;

#define BB   64
#define TT   256
#define II   512
#define HH   1024
#define KCB  512
#define GH   4096
#define KTOT 1536

#define APAD 136    // u16 elems per A-tile row (272 B stride)
#define BPAD 1544   // u16 elems per B row (3088 B stride)

// ws layout (float units):
//   [0 .. 6291456)        WT f32 [4096][1536] (dead after B-split)
//   [.. +131072)          h: 2 x [64][1024] u32 (bf16hi<<16|bf16lo), sc1-written
//   [.. +32768)           dist^2 [64][512] f32
//   [.. +544)             main barrier: 17 lines x 32 u32
#define WS_WT   0
#define WS_H    (GH*KTOT)
#define WS_DIST (WS_H + 2*HH*BB)
#define WS_BAR  (WS_DIST + BB*KCB)

#define LD_AG(p)   __hip_atomic_load((p), __ATOMIC_RELAXED, __HIP_MEMORY_SCOPE_AGENT)
#define ST_AG(p,v) __hip_atomic_store((p), (v), __ATOMIC_RELAXED, __HIP_MEMORY_SCOPE_AGENT)

__device__ __forceinline__ float sigf(float x){ return 1.0f/(1.0f+expf(-x)); }
__device__ __forceinline__ u16 bf16r(float f){ u32 u = __float_as_uint(f); u += 0x7FFFu + ((u>>16)&1u); return (u16)(u>>16); }
__device__ __forceinline__ float bf16f(u16 h){ return __uint_as_float(((u32)h)<<16); }

// ---- main (cross-XCD, L3) hierarchical barrier: proven rounds 5/6 ----
__device__ __forceinline__ void bar_arrive(u32* bar, int bid, int tid, int e){
    asm volatile("s_waitcnt vmcnt(0)" ::: "memory");   // my sc1 stores are at L3
    __syncthreads();
    if (tid == 0) {
        u32 old = atomicAdd(bar + (bid & 7) * 32, 1u);
        if (old == (u32)(e * 32 - 1)) {
            u32 old2 = atomicAdd(bar + 8 * 32, 1u);
            if (old2 == (u32)(e * 8 - 1)) {
                #pragma unroll
                for (int gg = 0; gg < 8; ++gg)
                    ST_AG(bar + (9 + gg) * 32, (u32)e);
            }
        }
    }
}
// acquire: spin, then agent-acquire fence (buffer_inv: L1+L2 invalidate) so that
// PLAIN loads below observe everything producers pushed to L3. One fence/block.
__device__ __forceinline__ void bar_wait(u32* bar, int bid, int tid, int e){
    if (tid == 0) {
        while ((int)LD_AG(bar + (9 + (bid & 7)) * 32) < e)
            __builtin_amdgcn_s_sleep(1);
        __builtin_amdgcn_fence(__ATOMIC_ACQUIRE, "agent");
    }
    __syncthreads();
}

__global__ __launch_bounds__(256, 1)
void lstm_vq(const float* __restrict__ seq, const int* __restrict__ nit,
             const float* __restrict__ Wx, const float* __restrict__ Wh,
             const float* __restrict__ bias, const float* __restrict__ cb,
             float* __restrict__ out, float* __restrict__ ws)
{
    cg::grid_group grid = cg::this_grid();
    __shared__ __align__(16) u16 aHi[64*APAD];
    __shared__ __align__(16) u16 aLo[64*APAD];
    __shared__ __align__(16) u16 bHi[16*BPAD];
    __shared__ __align__(16) u16 bLo[16*BPAD];
    __shared__ float ex[BB*16];
    __shared__ int sBest;

    const int tid = threadIdx.x;
    const int l   = tid & 63;
    const int w   = tid >> 6;
    const int bid = (int)blockIdx.x;

    float* WT   = ws + WS_WT;
    u32*   hbuf = (u32*)(ws + WS_H);
    float* dist = ws + WS_DIST;
    u32*   bar  = (u32*)(ws + WS_BAR);
    float* qz   = out + BB;
    float* uq   = out + BB + BB*HH;

    if (bid == 0 && tid < 17) ST_AG(bar + tid * 32, 0u);  // reset; ordered by grid.sync

    // ---------------- one-time: WT[zcol][k] = W[k][zcol] ----------------
    {
        const int c0 = bid * 16;
        float* tile = (float*)aHi;
        for (int kt = 0; kt < KTOT; kt += 64) {
            __syncthreads();
            #pragma unroll
            for (int ii2 = 0; ii2 < 4; ++ii2) {
                int ky = ii2*16 + (tid>>4);
                int cx = tid & 15;
                int kk = kt + ky;
                float v = (kk < II) ? Wx[(size_t)kk*GH + c0 + cx]
                                    : Wh[(size_t)(kk-II)*GH + c0 + cx];
                tile[cx*68 + ky] = v;
            }
            __syncthreads();
            {
                int cx = tid >> 4;
                int k4 = (tid & 15) * 4;
                f32x4 v = *(f32x4*)&tile[cx*68 + k4];
                *(f32x4*)&WT[(size_t)(c0+cx)*KTOT + kt + k4] = v;
            }
        }
        grid.sync();   // full fences: WT visible; orders barrier reset
    }

    // ---------------- one-time: split this block's 16 z-cols into bHi/bLo ----------------
    {
        __syncthreads();
        const int n  = tid >> 4;
        const int zc = ((n>>2)<<10) + (bid<<2) + (n&3);
        const float* wr = WT + (size_t)zc*KTOT;
        for (int k = (tid&15)*8; k < KTOT; k += 128) {
            f32x4 v0 = *(const f32x4*)(wr + k);
            f32x4 v1 = *(const f32x4*)(wr + k + 4);
            short8 ph, pl;
            #pragma unroll
            for (int e = 0; e < 8; ++e) {
                float fv = (e<4) ? v0[e] : v1[e-4];
                u16 hb = bf16r(fv);
                ph[e] = (short)hb;
                pl[e] = (short)bf16r(fv - bf16f(hb));
            }
            *(short8*)&bHi[n*BPAD + k] = ph;
            *(short8*)&bLo[n*BPAD + k] = pl;
        }
        __syncthreads();
    }

    // ---------------- per-thread roles ----------------
    const int rEx  = tid >> 2;
    const int ccEx = tid & 3;
    const int hcol = (bid<<2) + ccEx;
    const int myN  = nit[rEx];
    int maxN = 0;
    for (int i = 0; i < BB; ++i) maxN = max(maxN, nit[i]);

    const float bi_ = bias[hcol], bf_ = bias[HH+hcol], bg_ = bias[2*HH+hcol], bo_ = bias[3*HH+hcol];

    const int arow = (w<<4) + (l&15);
    const int ag   = (l>>4)<<3;
    const int bn   = l & 15;

    const int srow = tid >> 2;
    const int seg  = (tid & 3) << 5;

    float cst = 0.0f;
    f32x4 vr[8];            // x-phase staging regs (f32)
    u64 hvA[16], hvB[16];   // h-phase 2-deep prefetch regs (packed bf16 pairs)

#define HLOAD(dst, hc) { \
    const u64* hp_ = (const u64*)(hprev + (size_t)srow*HH + ((hc)<<7) + seg); \
    _Pragma("unroll") for (int j=0;j<16;++j) dst[j] = hp_[j]; }

#define HSTAGE(srcv) { \
    _Pragma("unroll") for (int q=0;q<4;++q){ \
        short8 ph, pl; \
        _Pragma("unroll") for (int ee=0;ee<8;++ee){ \
            u32 v = (u32)(srcv[q*4+(ee>>1)] >> ((ee&1)?32:0)); \
            ph[ee]=(short)(v>>16); pl[ee]=(short)(v&0xFFFFu); } \
        *(short8*)&aHi[srow*APAD+seg+q*8]=ph; \
        *(short8*)&aLo[srow*APAD+seg+q*8]=pl; } }

#define HMFMA(hc) { \
    _Pragma("unroll") for (int ks=0;ks<4;++ks){ \
        int ao=arow*APAD+(ks<<5)+ag; \
        int bo=bn*BPAD+(((hc)+4)<<7)+(ks<<5)+ag; \
        short8 ah=*(const short8*)&aHi[ao]; \
        short8 al=*(const short8*)&aLo[ao]; \
        short8 bhv=*(const short8*)&bHi[bo]; \
        short8 blv=*(const short8*)&bLo[bo]; \
        acc0=__builtin_amdgcn_mfma_f32_16x16x32_bf16(ah,bhv,acc0,0,0,0); \
        acc1=__builtin_amdgcn_mfma_f32_16x16x32_bf16(al,bhv,acc1,0,0,0); \
        acc2=__builtin_amdgcn_mfma_f32_16x16x32_bf16(ah,blv,acc2,0,0,0); } }

    for (int t = 0; t <= maxN; ++t) {
        const u32* hprev = hbuf + (size_t)(t&1)*(HH*BB);
        u32*       hnext = hbuf + (size_t)(1-(t&1))*(HH*BB);

        f32x4 acc0 = {0.f,0.f,0.f,0.f};
        f32x4 acc1 = {0.f,0.f,0.f,0.f};
        f32x4 acc2 = {0.f,0.f,0.f,0.f};

        // ======== x phase (chunks 0..3) — independent of h(t-1), runs pre-wait ========
        {
            const float* s0 = seq + (size_t)srow*(TT*II) + (size_t)t*II + seg;
            #pragma unroll
            for (int j = 0; j < 8; ++j) vr[j] = ((const f32x4*)s0)[j];
        }
        for (int c = 0; c < 4; ++c) {
            __syncthreads();
            #pragma unroll
            for (int q = 0; q < 4; ++q) {
                short8 ph, pl;
                #pragma unroll
                for (int e = 0; e < 8; ++e) {
                    float fv = (e<4) ? vr[2*q][e] : vr[2*q+1][e-4];
                    u16 hb = bf16r(fv);
                    ph[e] = (short)hb;
                    pl[e] = (short)bf16r(fv - bf16f(hb));
                }
                *(short8*)&aHi[srow*APAD + seg + q*8] = ph;
                *(short8*)&aLo[srow*APAD + seg + q*8] = pl;
            }
            if (c < 3) {
                const float* sn = seq + (size_t)srow*(TT*II) + (size_t)t*II + ((c+1)<<7) + seg;
                #pragma unroll
                for (int j = 0; j < 8; ++j) vr[j] = ((const f32x4*)sn)[j];
            }
            __syncthreads();
            #pragma unroll
            for (int ks = 0; ks < 4; ++ks) {
                int ao = arow*APAD + (ks<<5) + ag;
                int bo = bn*BPAD + (c<<7) + (ks<<5) + ag;
                short8 ah  = *(const short8*)&aHi[ao];
                short8 al  = *(const short8*)&aLo[ao];
                short8 bhv = *(const short8*)&bHi[bo];
                short8 blv = *(const short8*)&bLo[bo];
                acc0 = __builtin_amdgcn_mfma_f32_16x16x32_bf16(ah, bhv, acc0, 0,0,0);
                acc1 = __builtin_amdgcn_mfma_f32_16x16x32_bf16(al, bhv, acc1, 0,0,0);
                acc2 = __builtin_amdgcn_mfma_f32_16x16x32_bf16(ah, blv, acc2, 0,0,0);
            }
        }

        // ======== wait (spin + agent-acquire inv), then h phase: PLAIN L2-cached loads ========
        if (t > 0) {
            bar_wait(bar, bid, tid, t);     // h(t-1) in L3; L1+L2 invalidated
            HLOAD(hvA, 0); HLOAD(hvB, 1);
            __syncthreads(); HSTAGE(hvA); HLOAD(hvA, 2); __syncthreads(); HMFMA(0);
            __syncthreads(); HSTAGE(hvB); HLOAD(hvB, 3); __syncthreads(); HMFMA(1);
            __syncthreads(); HSTAGE(hvA); HLOAD(hvA, 4); __syncthreads(); HMFMA(2);
            __syncthreads(); HSTAGE(hvB); HLOAD(hvB, 5); __syncthreads(); HMFMA(3);
            __syncthreads(); HSTAGE(hvA); HLOAD(hvA, 6); __syncthreads(); HMFMA(4);
            __syncthreads(); HSTAGE(hvB); HLOAD(hvB, 7); __syncthreads(); HMFMA(5);
            __syncthreads(); HSTAGE(hvA);                __syncthreads(); HMFMA(6);
            __syncthreads(); HSTAGE(hvB);                __syncthreads(); HMFMA(7);
        }

        // ---- exchange: D (col=l&15, row=(l>>4)*4+j) -> per-(r,hcol) thread ----
        __syncthreads();
        {
            const int n  = l & 15;
            const int r0 = (w<<4) + ((l>>4)<<2);
            #pragma unroll
            for (int j = 0; j < 4; ++j)
                ex[(r0+j)*16 + n] = acc0[j] + acc1[j] + acc2[j];
        }
        __syncthreads();
        {
            float zi = ex[rEx*16 + 0*4 + ccEx] + bi_;
            float zf = ex[rEx*16 + 1*4 + ccEx] + bf_;
            float zg = ex[rEx*16 + 2*4 + ccEx] + bg_;
            float zo = ex[rEx*16 + 3*4 + ccEx] + bo_;
            float iv = sigf(zi), fv = sigf(zf), gv = tanhf(zg), ov = sigf(zo);
            cst = fv*cst + iv*gv;
            float h = ov * tanhf(cst);
            u16 hb = bf16r(h);
            u16 lb = bf16r(h - bf16f(hb));
            ST_AG(&hnext[(size_t)rEx*HH + hcol], ((u32)hb << 16) | (u32)lb);
            if (t == myN) ST_AG(&uq[(size_t)rEx*HH + hcol], h);
        }
        bar_arrive(bar, bid, tid, t + 1);
    }

    // ---------- VQ: distance^2 matrix [64][512] ----------
    bar_wait(bar, bid, tid, maxN + 1);      // includes acquire fence -> plain reads OK
    {
        const int wid = bid*4 + w;
        for (int p = wid*32; p < wid*32 + 32; ++p) {
            int rr = p >> 9;
            int kk = p & 511;
            const u64* u8p = (const u64*)(uq + (size_t)rr*HH);
            const f32x4* c4 = (const f32x4*)(cb + (size_t)kk*HH);
            float s = 0.0f;
            #pragma unroll
            for (int q = 0; q < 4; ++q) {
                u64 e0 = u8p[2*(l + q*64)];
                u64 e1 = u8p[2*(l + q*64) + 1];
                f32x4 b = c4[l + q*64];
                float a0 = __uint_as_float((u32)e0), a1 = __uint_as_float((u32)(e0>>32));
                float a2 = __uint_as_float((u32)e1), a3 = __uint_as_float((u32)(e1>>32));
                float d0 = a0-b[0], d1 = a1-b[1], d2 = a2-b[2], d3 = a3-b[3];
                s += d0*d0 + d1*d1 + d2*d2 + d3*d3;
            }
            #pragma unroll
            for (int off = 32; off > 0; off >>= 1) s += __shfl_xor(s, off, 64);
            if (l == 0) ST_AG(&dist[(size_t)rr*KCB + kk], s);
        }
    }
    bar_arrive(bar, bid, tid, maxN + 2);
    bar_wait(bar, bid, tid, maxN + 2);      // fence -> plain dist reads OK

    // ---------- argmin + emit outputs (blocks 0..63, one row each) ----------
    if (bid < BB) {
        const int rr = bid;
        if (tid < 64) {
            float best = 3.4e38f;
            int   bi   = 0;
            for (int kk = tid; kk < KCB; kk += 64) {
                float v = dist[(size_t)rr*KCB + kk];
                if (v < best) { best = v; bi = kk; }
            }
            #pragma unroll
            for (int off = 32; off > 0; off >>= 1) {
                float ovv = __shfl_xor(best, off, 64);
                int   oii = __shfl_xor(bi,   off, 64);
                if (ovv < best || (ovv == best && oii < bi)) { best = ovv; bi = oii; }
            }
            if (tid == 0) { sBest = bi; out[rr] = (float)bi; }
        }
        __syncthreads();
        const int bk = sBest;
        const f32x4* c4 = (const f32x4*)(cb + (size_t)bk*HH);
        f32x4*       q4 = (f32x4*)(qz + (size_t)rr*HH);
        for (int d = tid; d < HH/4; d += 256) q4[d] = c4[d];
    }
}

extern "C" void kernel_launch(void* const* d_in, const int* in_sizes, int n_in,
                              void* d_out, int out_size, void* d_ws, size_t ws_size,
                              hipStream_t stream) {
    const float* seq  = (const float*)d_in[0];
    const int*   nit  = (const int*)  d_in[1];
    const float* Wx   = (const float*)d_in[2];
    const float* Wh   = (const float*)d_in[3];
    const float* bias = (const float*)d_in[4];
    const float* cb   = (const float*)d_in[5];
    float* out = (float*)d_out;
    float* ws  = (float*)d_ws;

    void* args[] = { &seq, &nit, &Wx, &Wh, &bias, &cb, &out, &ws };
    hipLaunchCooperativeKernel((void*)lstm_vq, dim3(256), dim3(256), args, 0, stream);
}

// Round 9
// 3866.269 us; speedup vs baseline: 14.7765x; 1.1622x over previous
//
#include <hip/hip_runtime.h>
#include <hip/hip_cooperative_groups.h>

namespace cg = cooperative_groups;

typedef unsigned short u16;
typedef unsigned int   u32;
typedef unsigned long long u64;
typedef __attribute__((ext_vector_type(8))) short short8;
typedef __attribute__((ext_vector_type(4))) float f32x4;
typedef __attribute__((ext_vector_type(4))) unsigned int u32x4;

#define BB   64
#define TT   256
#define II   512
#define HH   1024
#define KCB  512
#define GH   4096
#define KTOT 1536

#define BPAD 1544   // u16 elems per B row (3088 B stride)

// ws layout (float units):
//   [0 .. 6291456)        WT f32 [4096][1536] (dead after B-split)
//   [.. +131072)          h: 2 x [64][1024] u32 (bf16hi<<16|bf16lo), sc1-written
//   [.. +32768)           dist^2 [64][512] f32
//   [.. +544)             main barrier: 17 lines x 32 u32
#define WS_WT   0
#define WS_H    (GH*KTOT)
#define WS_DIST (WS_H + 2*HH*BB)
#define WS_BAR  (WS_DIST + BB*KCB)

#define LD_AG(p)   __hip_atomic_load((p), __ATOMIC_RELAXED, __HIP_MEMORY_SCOPE_AGENT)
#define ST_AG(p,v) __hip_atomic_store((p), (v), __ATOMIC_RELAXED, __HIP_MEMORY_SCOPE_AGENT)

__device__ __forceinline__ float sigf(float x){ return 1.0f/(1.0f+expf(-x)); }
__device__ __forceinline__ u16 bf16r(float f){ u32 u = __float_as_uint(f); u += 0x7FFFu + ((u>>16)&1u); return (u16)(u>>16); }
__device__ __forceinline__ float bf16f(u16 h){ return __uint_as_float(((u32)h)<<16); }

// ---- main (cross-XCD, L3) hierarchical barrier: proven rounds 5-8 ----
__device__ __forceinline__ void bar_arrive(u32* bar, int bid, int tid, int e){
    asm volatile("s_waitcnt vmcnt(0)" ::: "memory");   // my sc1 stores are at L3
    __syncthreads();
    if (tid == 0) {
        u32 old = atomicAdd(bar + (bid & 7) * 32, 1u);
        if (old == (u32)(e * 32 - 1)) {
            u32 old2 = atomicAdd(bar + 8 * 32, 1u);
            if (old2 == (u32)(e * 8 - 1)) {
                #pragma unroll
                for (int gg = 0; gg < 8; ++gg)
                    ST_AG(bar + (9 + gg) * 32, (u32)e);
            }
        }
    }
}
// acquire: spin, then agent-acquire fence (L1+L2 invalidate) -> plain loads fresh
__device__ __forceinline__ void bar_wait(u32* bar, int bid, int tid, int e){
    if (tid == 0) {
        while ((int)LD_AG(bar + (9 + (bid & 7)) * 32) < e)
            __builtin_amdgcn_s_sleep(1);
        __builtin_amdgcn_fence(__ATOMIC_ACQUIRE, "agent");
    }
    __syncthreads();
}

__global__ __launch_bounds__(256, 1)
void lstm_vq(const float* __restrict__ seq, const int* __restrict__ nit,
             const float* __restrict__ Wx, const float* __restrict__ Wh,
             const float* __restrict__ bias, const float* __restrict__ cb,
             float* __restrict__ out, float* __restrict__ ws)
{
    cg::grid_group grid = cg::this_grid();
    __shared__ __align__(16) u16 bHi[16*BPAD];   // 49408 B
    __shared__ __align__(16) u16 bLo[16*BPAD];   // 49408 B
    __shared__ float ex[BB*16];
    __shared__ int sBest;

    const int tid = threadIdx.x;
    const int l   = tid & 63;
    const int w   = tid >> 6;
    const int bid = (int)blockIdx.x;

    float* WT   = ws + WS_WT;
    u32*   hbuf = (u32*)(ws + WS_H);
    float* dist = ws + WS_DIST;
    u32*   bar  = (u32*)(ws + WS_BAR);
    float* qz   = out + BB;
    float* uq   = out + BB + BB*HH;

    if (bid == 0 && tid < 17) ST_AG(bar + tid * 32, 0u);  // reset; ordered by grid.sync

    // ---------------- one-time: WT[zcol][k] = W[k][zcol] ----------------
    {
        const int c0 = bid * 16;
        float* tile = (float*)bHi;               // scratch (pre-B-split)
        for (int kt = 0; kt < KTOT; kt += 64) {
            __syncthreads();
            #pragma unroll
            for (int ii2 = 0; ii2 < 4; ++ii2) {
                int ky = ii2*16 + (tid>>4);
                int cx = tid & 15;
                int kk = kt + ky;
                float v = (kk < II) ? Wx[(size_t)kk*GH + c0 + cx]
                                    : Wh[(size_t)(kk-II)*GH + c0 + cx];
                tile[cx*68 + ky] = v;
            }
            __syncthreads();
            {
                int cx = tid >> 4;
                int k4 = (tid & 15) * 4;
                f32x4 v = *(f32x4*)&tile[cx*68 + k4];
                *(f32x4*)&WT[(size_t)(c0+cx)*KTOT + kt + k4] = v;
            }
        }
        grid.sync();   // full fences: WT visible; orders barrier reset
    }

    // ---------------- one-time: split this block's 16 z-cols into bHi/bLo ----------------
    {
        __syncthreads();
        const int n  = tid >> 4;
        const int zc = ((n>>2)<<10) + (bid<<2) + (n&3);
        const float* wr = WT + (size_t)zc*KTOT;
        for (int k = (tid&15)*8; k < KTOT; k += 128) {
            f32x4 v0 = *(const f32x4*)(wr + k);
            f32x4 v1 = *(const f32x4*)(wr + k + 4);
            short8 ph, pl;
            #pragma unroll
            for (int e = 0; e < 8; ++e) {
                float fv = (e<4) ? v0[e] : v1[e-4];
                u16 hb = bf16r(fv);
                ph[e] = (short)hb;
                pl[e] = (short)bf16r(fv - bf16f(hb));
            }
            *(short8*)&bHi[n*BPAD + k] = ph;
            *(short8*)&bLo[n*BPAD + k] = pl;
        }
        __syncthreads();
    }

    // ---------------- per-thread roles ----------------
    const int rEx  = tid >> 2;
    const int ccEx = tid & 3;
    const int hcol = (bid<<2) + ccEx;
    const int myN  = nit[rEx];
    int maxN = 0;
    for (int i = 0; i < BB; ++i) maxN = max(maxN, nit[i]);

    const float bi_ = bias[hcol], bf_ = bias[HH+hcol], bg_ = bias[2*HH+hcol], bo_ = bias[3*HH+hcol];

    const int arow = (w<<4) + (l&15);        // A row (batch row) this thread owns
    const int ag   = (l>>4)<<3;              // k sub-offset within K=32 slice
    const int bn   = l & 15;                 // B col this lane reads

    float cst = 0.0f;
    f32x4  xA0, xA1, xB0, xB1;               // x-phase 2-deep reg pipeline
    u32x4  hA0, hA1, hB0, hB1;               // h-phase 2-deep reg pipeline

// direct per-thread A-fragment loads: zero LDS staging, zero syncs
#define XLD(buf, it) { \
    const float* xp_ = seq + (size_t)arow*(TT*II) + (size_t)t*II + ((it)<<5) + ag; \
    buf##0 = *(const f32x4*)xp_; buf##1 = *(const f32x4*)(xp_ + 4); }

#define XCOMP(buf, it) { \
    short8 ph, pl; \
    _Pragma("unroll") for (int e=0;e<8;++e){ \
        float fv = (e<4) ? buf##0[e] : buf##1[e-4]; \
        u16 hb = bf16r(fv); ph[e]=(short)hb; pl[e]=(short)bf16r(fv - bf16f(hb)); } \
    int bo = bn*BPAD + ((it)<<5) + ag; \
    short8 bhv = *(const short8*)&bHi[bo]; \
    short8 blv = *(const short8*)&bLo[bo]; \
    acc0 = __builtin_amdgcn_mfma_f32_16x16x32_bf16(ph, bhv, acc0, 0,0,0); \
    acc1 = __builtin_amdgcn_mfma_f32_16x16x32_bf16(pl, bhv, acc1, 0,0,0); \
    acc2 = __builtin_amdgcn_mfma_f32_16x16x32_bf16(ph, blv, acc2, 0,0,0); }

#define HLD(buf, it) { \
    const u32* hp_ = hprev + (size_t)arow*HH + ((it)<<5) + ag; \
    buf##0 = *(const u32x4*)hp_; buf##1 = *(const u32x4*)(hp_ + 4); }

#define HCOMP(buf, it) { \
    short8 ph, pl; \
    _Pragma("unroll") for (int e=0;e<8;++e){ \
        u32 v = (e<4) ? buf##0[e] : buf##1[e-4]; \
        ph[e]=(short)(v>>16); pl[e]=(short)(v & 0xFFFFu); } \
    int bo = bn*BPAD + 512 + ((it)<<5) + ag; \
    short8 bhv = *(const short8*)&bHi[bo]; \
    short8 blv = *(const short8*)&bLo[bo]; \
    acc0 = __builtin_amdgcn_mfma_f32_16x16x32_bf16(ph, bhv, acc0, 0,0,0); \
    acc1 = __builtin_amdgcn_mfma_f32_16x16x32_bf16(pl, bhv, acc1, 0,0,0); \
    acc2 = __builtin_amdgcn_mfma_f32_16x16x32_bf16(ph, blv, acc2, 0,0,0); }

    for (int t = 0; t <= maxN; ++t) {
        const u32* hprev = hbuf + (size_t)(t&1)*(HH*BB);
        u32*       hnext = hbuf + (size_t)(1-(t&1))*(HH*BB);

        f32x4 acc0 = {0.f,0.f,0.f,0.f};
        f32x4 acc1 = {0.f,0.f,0.f,0.f};
        f32x4 acc2 = {0.f,0.f,0.f,0.f};

        // ======== x GEMM (k 0..511) — pre-wait, sync-free, 2-deep pipeline ========
        XLD(xA, 0);
        #pragma unroll
        for (int it = 0; it < 16; it += 2) {
            XLD(xB, it+1);
            XCOMP(xA, it);
            if (it + 2 < 16) XLD(xA, it+2);
            XCOMP(xB, it+1);
        }

        // ======== wait (spin + inv), then h GEMM (k 512..1535) — sync-free ========
        if (t > 0) {
            bar_wait(bar, bid, tid, t);     // h(t-1) in L3; L1+L2 invalidated
            HLD(hA, 0);
            #pragma unroll
            for (int it = 0; it < 32; it += 2) {
                HLD(hB, it+1);
                HCOMP(hA, it);
                if (it + 2 < 32) HLD(hA, it+2);
                HCOMP(hB, it+1);
            }
        }

        // ---- exchange: D (col=l&15, row=(l>>4)*4+j) -> per-(r,hcol) thread ----
        __syncthreads();
        {
            const int n  = l & 15;
            const int r0 = (w<<4) + ((l>>4)<<2);
            #pragma unroll
            for (int j = 0; j < 4; ++j)
                ex[(r0+j)*16 + n] = acc0[j] + acc1[j] + acc2[j];
        }
        __syncthreads();
        {
            float zi = ex[rEx*16 + 0*4 + ccEx] + bi_;
            float zf = ex[rEx*16 + 1*4 + ccEx] + bf_;
            float zg = ex[rEx*16 + 2*4 + ccEx] + bg_;
            float zo = ex[rEx*16 + 3*4 + ccEx] + bo_;
            float iv = sigf(zi), fv = sigf(zf), gv = tanhf(zg), ov = sigf(zo);
            cst = fv*cst + iv*gv;
            float h = ov * tanhf(cst);
            u16 hb = bf16r(h);
            u16 lb = bf16r(h - bf16f(hb));
            ST_AG(&hnext[(size_t)rEx*HH + hcol], ((u32)hb << 16) | (u32)lb);
            if (t == myN) ST_AG(&uq[(size_t)rEx*HH + hcol], h);
        }
        bar_arrive(bar, bid, tid, t + 1);
    }

    // ---------- VQ: distance^2 matrix [64][512] ----------
    bar_wait(bar, bid, tid, maxN + 1);      // includes acquire fence -> plain reads OK
    {
        const int wid = bid*4 + w;
        for (int p = wid*32; p < wid*32 + 32; ++p) {
            int rr = p >> 9;
            int kk = p & 511;
            const u64* u8p = (const u64*)(uq + (size_t)rr*HH);
            const f32x4* c4 = (const f32x4*)(cb + (size_t)kk*HH);
            float s = 0.0f;
            #pragma unroll
            for (int q = 0; q < 4; ++q) {
                u64 e0 = u8p[2*(l + q*64)];
                u64 e1 = u8p[2*(l + q*64) + 1];
                f32x4 b = c4[l + q*64];
                float a0 = __uint_as_float((u32)e0), a1 = __uint_as_float((u32)(e0>>32));
                float a2 = __uint_as_float((u32)e1), a3 = __uint_as_float((u32)(e1>>32));
                float d0 = a0-b[0], d1 = a1-b[1], d2 = a2-b[2], d3 = a3-b[3];
                s += d0*d0 + d1*d1 + d2*d2 + d3*d3;
            }
            #pragma unroll
            for (int off = 32; off > 0; off >>= 1) s += __shfl_xor(s, off, 64);
            if (l == 0) ST_AG(&dist[(size_t)rr*KCB + kk], s);
        }
    }
    bar_arrive(bar, bid, tid, maxN + 2);
    bar_wait(bar, bid, tid, maxN + 2);      // fence -> plain dist reads OK

    // ---------- argmin + emit outputs (blocks 0..63, one row each) ----------
    if (bid < BB) {
        const int rr = bid;
        if (tid < 64) {
            float best = 3.4e38f;
            int   bi   = 0;
            for (int kk = tid; kk < KCB; kk += 64) {
                float v = dist[(size_t)rr*KCB + kk];
                if (v < best) { best = v; bi = kk; }
            }
            #pragma unroll
            for (int off = 32; off > 0; off >>= 1) {
                float ovv = __shfl_xor(best, off, 64);
                int   oii = __shfl_xor(bi,   off, 64);
                if (ovv < best || (ovv == best && oii < bi)) { best = ovv; bi = oii; }
            }
            if (tid == 0) { sBest = bi; out[rr] = (float)bi; }
        }
        __syncthreads();
        const int bk = sBest;
        const f32x4* c4 = (const f32x4*)(cb + (size_t)bk*HH);
        f32x4*       q4 = (f32x4*)(qz + (size_t)rr*HH);
        for (int d = tid; d < HH/4; d += 256) q4[d] = c4[d];
    }
}

extern "C" void kernel_launch(void* const* d_in, const int* in_sizes, int n_in,
                              void* d_out, int out_size, void* d_ws, size_t ws_size,
                              hipStream_t stream) {
    const float* seq  = (const float*)d_in[0];
    const int*   nit  = (const int*)  d_in[1];
    const float* Wx   = (const float*)d_in[2];
    const float* Wh   = (const float*)d_in[3];
    const float* bias = (const float*)d_in[4];
    const float* cb   = (const float*)d_in[5];
    float* out = (float*)d_out;
    float* ws  = (float*)d_ws;

    void* args[] = { &seq, &nit, &Wx, &Wh, &bias, &cb, &out, &ws };
    hipLaunchCooperativeKernel((void*)lstm_vq, dim3(256), dim3(256), args, 0, stream);
}

// Round 10
// 3806.914 us; speedup vs baseline: 15.0069x; 1.0156x over previous
//
#include <hip/hip_runtime.h>
#include <hip/hip_cooperative_groups.h>

namespace cg = cooperative_groups;

typedef unsigned short u16;
typedef unsigned int   u32;
typedef unsigned long long u64;
typedef __attribute__((ext_vector_type(8))) short short8;
typedef __attribute__((ext_vector_type(4))) float f32x4;

#define BB   64
#define TT   256
#define II   512
#define HH   1024
#define KCB  512
#define GH   4096
#define KTOT 1536

#define BPAD 1544   // u16 elems per B row (3088 B stride)

// ws layout (float units):
//   [0 .. 6291456)        WT f32 [4096][1536] (dead after B-split)
//   [.. +131072)          h: 2 bufs x (hi plane 65536 u16 + lo plane 65536 u16)
//   [.. +32768)           dist^2 [64][512] f32
//   [.. +544)             main barrier: 17 lines x 32 u32
#define WS_WT   0
#define WS_H    (GH*KTOT)
#define WS_DIST (WS_H + 2*HH*BB)
#define WS_BAR  (WS_DIST + BB*KCB)

#define LD_AG(p)   __hip_atomic_load((p), __ATOMIC_RELAXED, __HIP_MEMORY_SCOPE_AGENT)
#define ST_AG(p,v) __hip_atomic_store((p), (v), __ATOMIC_RELAXED, __HIP_MEMORY_SCOPE_AGENT)

__device__ __forceinline__ float sigf(float x){ return 1.0f/(1.0f+expf(-x)); }
__device__ __forceinline__ u16 bf16r(float f){ u32 u = __float_as_uint(f); u += 0x7FFFu + ((u>>16)&1u); return (u16)(u>>16); }
__device__ __forceinline__ float bf16f(u16 h){ return __uint_as_float(((u32)h)<<16); }

// ---- main (cross-XCD, L3) hierarchical barrier: proven rounds 5-9 ----
__device__ __forceinline__ void bar_arrive(u32* bar, int bid, int tid, int e){
    asm volatile("s_waitcnt vmcnt(0)" ::: "memory");   // my sc1 stores are at L3
    __syncthreads();
    if (tid == 0) {
        u32 old = atomicAdd(bar + (bid & 7) * 32, 1u);
        if (old == (u32)(e * 32 - 1)) {
            u32 old2 = atomicAdd(bar + 8 * 32, 1u);
            if (old2 == (u32)(e * 8 - 1)) {
                #pragma unroll
                for (int gg = 0; gg < 8; ++gg)
                    ST_AG(bar + (9 + gg) * 32, (u32)e);
            }
        }
    }
}
// acquire: spin, then agent-acquire fence (L1+L2 invalidate) -> plain loads fresh
__device__ __forceinline__ void bar_wait(u32* bar, int bid, int tid, int e){
    if (tid == 0) {
        while ((int)LD_AG(bar + (9 + (bid & 7)) * 32) < e)
            __builtin_amdgcn_s_sleep(1);
        __builtin_amdgcn_fence(__ATOMIC_ACQUIRE, "agent");
    }
    __syncthreads();
}

__global__ __launch_bounds__(256, 1)
void lstm_vq(const float* __restrict__ seq, const int* __restrict__ nit,
             const float* __restrict__ Wx, const float* __restrict__ Wh,
             const float* __restrict__ bias, const float* __restrict__ cb,
             float* __restrict__ out, float* __restrict__ ws)
{
    cg::grid_group grid = cg::this_grid();
    __shared__ __align__(16) u16 bHi[16*BPAD];   // 49408 B
    __shared__ __align__(16) u16 bLo[16*BPAD];   // 49408 B
    __shared__ float ex[BB*16];
    __shared__ int sBest;

    const int tid = threadIdx.x;
    const int l   = tid & 63;
    const int w   = tid >> 6;
    const int bid = (int)blockIdx.x;

    float* WT   = ws + WS_WT;
    u16*   hbuf = (u16*)(ws + WS_H);             // 2 bufs x 131072 u16
    float* dist = ws + WS_DIST;
    u32*   bar  = (u32*)(ws + WS_BAR);
    float* qz   = out + BB;
    float* uq   = out + BB + BB*HH;

    if (bid == 0 && tid < 17) ST_AG(bar + tid * 32, 0u);  // reset; ordered by grid.sync

    // ---------------- one-time: WT[zcol][k] = W[k][zcol] ----------------
    {
        const int c0 = bid * 16;
        float* tile = (float*)bHi;               // scratch (pre-B-split)
        for (int kt = 0; kt < KTOT; kt += 64) {
            __syncthreads();
            #pragma unroll
            for (int ii2 = 0; ii2 < 4; ++ii2) {
                int ky = ii2*16 + (tid>>4);
                int cx = tid & 15;
                int kk = kt + ky;
                float v = (kk < II) ? Wx[(size_t)kk*GH + c0 + cx]
                                    : Wh[(size_t)(kk-II)*GH + c0 + cx];
                tile[cx*68 + ky] = v;
            }
            __syncthreads();
            {
                int cx = tid >> 4;
                int k4 = (tid & 15) * 4;
                f32x4 v = *(f32x4*)&tile[cx*68 + k4];
                *(f32x4*)&WT[(size_t)(c0+cx)*KTOT + kt + k4] = v;
            }
        }
        grid.sync();   // full fences: WT visible; orders barrier reset
    }

    // ---------------- one-time: split this block's 16 z-cols into bHi/bLo ----------------
    {
        __syncthreads();
        const int n  = tid >> 4;
        const int zc = ((n>>2)<<10) + (bid<<2) + (n&3);
        const float* wr = WT + (size_t)zc*KTOT;
        for (int k = (tid&15)*8; k < KTOT; k += 128) {
            f32x4 v0 = *(const f32x4*)(wr + k);
            f32x4 v1 = *(const f32x4*)(wr + k + 4);
            short8 ph, pl;
            #pragma unroll
            for (int e = 0; e < 8; ++e) {
                float fv = (e<4) ? v0[e] : v1[e-4];
                u16 hb = bf16r(fv);
                ph[e] = (short)hb;
                pl[e] = (short)bf16r(fv - bf16f(hb));
            }
            *(short8*)&bHi[n*BPAD + k] = ph;
            *(short8*)&bLo[n*BPAD + k] = pl;
        }
        __syncthreads();
    }

    // ---------------- per-thread roles ----------------
    const int rEx  = tid >> 2;
    const int ccEx = tid & 3;
    const int hcol = (bid<<2) + ccEx;
    const int myN  = nit[rEx];
    int maxN = 0;
    for (int i = 0; i < BB; ++i) maxN = max(maxN, nit[i]);

    const float bi_ = bias[hcol], bf_ = bias[HH+hcol], bg_ = bias[2*HH+hcol], bo_ = bias[3*HH+hcol];

    const int arow = (w<<4) + (l&15);        // A row (batch row) this thread owns
    const int ag   = (l>>4)<<3;              // k sub-offset within K=32 slice
    const int bn   = l & 15;                 // B col this lane reads

    float cst = 0.0f;
    f32x4 xA0, xA1, xB0, xB1;                        // x-phase 2-deep reg pipeline
    short8 p0h,p0l,p1h,p1l,p2h,p2l,p3h,p3l;          // h-phase 8-deep ring
    short8 p4h,p4l,p5h,p5l,p6h,p6l,p7h,p7l;          //  (hi/lo direct MFMA operands)

// ---- x phase: direct per-thread A loads + hi/lo split (unchanged r9) ----
#define XLD(buf, it) { \
    const float* xp_ = seq + (size_t)arow*(TT*II) + (size_t)t*II + ((it)<<5) + ag; \
    buf##0 = *(const f32x4*)xp_; buf##1 = *(const f32x4*)(xp_ + 4); }

#define XCOMP(buf, it) { \
    short8 ph, pl; \
    _Pragma("unroll") for (int e=0;e<8;++e){ \
        float fv = (e<4) ? buf##0[e] : buf##1[e-4]; \
        u16 hb = bf16r(fv); ph[e]=(short)hb; pl[e]=(short)bf16r(fv - bf16f(hb)); } \
    int bo = bn*BPAD + ((it)<<5) + ag; \
    short8 bhv = *(const short8*)&bHi[bo]; \
    short8 blv = *(const short8*)&bLo[bo]; \
    acc0 = __builtin_amdgcn_mfma_f32_16x16x32_bf16(ph, bhv, acc0, 0,0,0); \
    acc1 = __builtin_amdgcn_mfma_f32_16x16x32_bf16(pl, bhv, acc1, 0,0,0); \
    acc2 = __builtin_amdgcn_mfma_f32_16x16x32_bf16(ph, blv, acc2, 0,0,0); }

// ---- h phase: plane loads are DIRECT MFMA operands (zero VALU) ----
#define HLD(B, it) { \
    const u16* hp_ = hiP + (size_t)arow*HH + ((it)<<5) + ag; \
    B##h = *(const short8*)hp_; \
    B##l = *(const short8*)(hp_ + 65536); }

#define HMFMA(B, it) { \
    int bo = bn*BPAD + 512 + ((it)<<5) + ag; \
    short8 bhv = *(const short8*)&bHi[bo]; \
    short8 blv = *(const short8*)&bLo[bo]; \
    acc0 = __builtin_amdgcn_mfma_f32_16x16x32_bf16(B##h, bhv, acc0, 0,0,0); \
    acc1 = __builtin_amdgcn_mfma_f32_16x16x32_bf16(B##l, bhv, acc1, 0,0,0); \
    acc2 = __builtin_amdgcn_mfma_f32_16x16x32_bf16(B##h, blv, acc2, 0,0,0); }

#define HSTEP(B, it) { HMFMA(B, it); if ((it) + 8 < 32) HLD(B, (it)+8); }

    for (int t = 0; t <= maxN; ++t) {
        const u16* hiP  = hbuf + (size_t)(t&1)*131072;       // hi plane; lo at +65536
        u16*       hiN  = hbuf + (size_t)(1-(t&1))*131072;
        u16*       loN  = hiN + 65536;

        f32x4 acc0 = {0.f,0.f,0.f,0.f};
        f32x4 acc1 = {0.f,0.f,0.f,0.f};
        f32x4 acc2 = {0.f,0.f,0.f,0.f};

        // ======== x GEMM (k 0..511) — pre-wait, sync-free, 2-deep pipeline ========
        XLD(xA, 0);
        #pragma unroll
        for (int it = 0; it < 16; it += 2) {
            XLD(xB, it+1);
            XCOMP(xA, it);
            if (it + 2 < 16) XLD(xA, it+2);
            XCOMP(xB, it+1);
        }

        // ======== wait (spin + inv), then h GEMM — 8-deep ring, zero VALU ========
        if (t > 0) {
            bar_wait(bar, bid, tid, t);     // h(t-1) in L3; L1+L2 invalidated
            HLD(p0,0) HLD(p1,1) HLD(p2,2) HLD(p3,3)
            HLD(p4,4) HLD(p5,5) HLD(p6,6) HLD(p7,7)
            HSTEP(p0,0)  HSTEP(p1,1)  HSTEP(p2,2)  HSTEP(p3,3)
            HSTEP(p4,4)  HSTEP(p5,5)  HSTEP(p6,6)  HSTEP(p7,7)
            HSTEP(p0,8)  HSTEP(p1,9)  HSTEP(p2,10) HSTEP(p3,11)
            HSTEP(p4,12) HSTEP(p5,13) HSTEP(p6,14) HSTEP(p7,15)
            HSTEP(p0,16) HSTEP(p1,17) HSTEP(p2,18) HSTEP(p3,19)
            HSTEP(p4,20) HSTEP(p5,21) HSTEP(p6,22) HSTEP(p7,23)
            HSTEP(p0,24) HSTEP(p1,25) HSTEP(p2,26) HSTEP(p3,27)
            HSTEP(p4,28) HSTEP(p5,29) HSTEP(p6,30) HSTEP(p7,31)
        }

        // ---- exchange: D (col=l&15, row=(l>>4)*4+j) -> per-(r,hcol) thread ----
        __syncthreads();
        {
            const int n  = l & 15;
            const int r0 = (w<<4) + ((l>>4)<<2);
            #pragma unroll
            for (int j = 0; j < 4; ++j)
                ex[(r0+j)*16 + n] = acc0[j] + acc1[j] + acc2[j];
        }
        __syncthreads();
        {
            float zi = ex[rEx*16 + 0*4 + ccEx] + bi_;
            float zf = ex[rEx*16 + 1*4 + ccEx] + bf_;
            float zg = ex[rEx*16 + 2*4 + ccEx] + bg_;
            float zo = ex[rEx*16 + 3*4 + ccEx] + bo_;
            float iv = sigf(zi), fv = sigf(zf), gv = tanhf(zg), ov = sigf(zo);
            cst = fv*cst + iv*gv;
            float h = ov * tanhf(cst);
            u16 hb = bf16r(h);
            u16 lb = bf16r(h - bf16f(hb));
            ST_AG(&hiN[(size_t)rEx*HH + hcol], hb);
            ST_AG(&loN[(size_t)rEx*HH + hcol], lb);
            if (t == myN) ST_AG(&uq[(size_t)rEx*HH + hcol], h);
        }
        bar_arrive(bar, bid, tid, t + 1);
    }

    // ---------- VQ: distance^2 matrix [64][512] ----------
    bar_wait(bar, bid, tid, maxN + 1);      // includes acquire fence -> plain reads OK
    {
        const int wid = bid*4 + w;
        for (int p = wid*32; p < wid*32 + 32; ++p) {
            int rr = p >> 9;
            int kk = p & 511;
            const u64* u8p = (const u64*)(uq + (size_t)rr*HH);
            const f32x4* c4 = (const f32x4*)(cb + (size_t)kk*HH);
            float s = 0.0f;
            #pragma unroll
            for (int q = 0; q < 4; ++q) {
                u64 e0 = u8p[2*(l + q*64)];
                u64 e1 = u8p[2*(l + q*64) + 1];
                f32x4 b = c4[l + q*64];
                float a0 = __uint_as_float((u32)e0), a1 = __uint_as_float((u32)(e0>>32));
                float a2 = __uint_as_float((u32)e1), a3 = __uint_as_float((u32)(e1>>32));
                float d0 = a0-b[0], d1 = a1-b[1], d2 = a2-b[2], d3 = a3-b[3];
                s += d0*d0 + d1*d1 + d2*d2 + d3*d3;
            }
            #pragma unroll
            for (int off = 32; off > 0; off >>= 1) s += __shfl_xor(s, off, 64);
            if (l == 0) ST_AG(&dist[(size_t)rr*KCB + kk], s);
        }
    }
    bar_arrive(bar, bid, tid, maxN + 2);
    bar_wait(bar, bid, tid, maxN + 2);      // fence -> plain dist reads OK

    // ---------- argmin + emit outputs (blocks 0..63, one row each) ----------
    if (bid < BB) {
        const int rr = bid;
        if (tid < 64) {
            float best = 3.4e38f;
            int   bi   = 0;
            for (int kk = tid; kk < KCB; kk += 64) {
                float v = dist[(size_t)rr*KCB + kk];
                if (v < best) { best = v; bi = kk; }
            }
            #pragma unroll
            for (int off = 32; off > 0; off >>= 1) {
                float ovv = __shfl_xor(best, off, 64);
                int   oii = __shfl_xor(bi,   off, 64);
                if (ovv < best || (ovv == best && oii < bi)) { best = ovv; bi = oii; }
            }
            if (tid == 0) { sBest = bi; out[rr] = (float)bi; }
        }
        __syncthreads();
        const int bk = sBest;
        const f32x4* c4 = (const f32x4*)(cb + (size_t)bk*HH);
        f32x4*       q4 = (f32x4*)(qz + (size_t)rr*HH);
        for (int d = tid; d < HH/4; d += 256) q4[d] = c4[d];
    }
}

extern "C" void kernel_launch(void* const* d_in, const int* in_sizes, int n_in,
                              void* d_out, int out_size, void* d_ws, size_t ws_size,
                              hipStream_t stream) {
    const float* seq  = (const float*)d_in[0];
    const int*   nit  = (const int*)  d_in[1];
    const float* Wx   = (const float*)d_in[2];
    const float* Wh   = (const float*)d_in[3];
    const float* bias = (const float*)d_in[4];
    const float* cb   = (const float*)d_in[5];
    float* out = (float*)d_out;
    float* ws  = (float*)d_ws;

    void* args[] = { &seq, &nit, &Wx, &Wh, &bias, &cb, &out, &ws };
    hipLaunchCooperativeKernel((void*)lstm_vq, dim3(256), dim3(256), args, 0, stream);
}

// Round 11
// 3627.422 us; speedup vs baseline: 15.7495x; 1.0495x over previous
//
#include <hip/hip_runtime.h>
#include <hip/hip_cooperative_groups.h>

namespace cg = cooperative_groups;

typedef unsigned short u16;
typedef unsigned int   u32;
typedef unsigned long long u64;
typedef __attribute__((ext_vector_type(8))) short short8;
typedef __attribute__((ext_vector_type(4))) float f32x4;

#define BB   64
#define TT   256
#define II   512
#define HH   1024
#define KCB  512
#define GH   4096
#define KTOT 1536

#define BPAD 1544   // u16 elems per B row (3088 B stride)

// ws layout (float units):
//   [0 .. 6291456)        WT f32 [4096][1536] (dead after B-split)
//   [.. +131072)          h: 2 bufs x (hi plane 65536 u16 + lo plane 65536 u16)
//   [.. +32768)           dist^2 [64][512] f32
//   [.. +544)             main barrier: 17 lines x 32 u32
#define WS_WT   0
#define WS_H    (GH*KTOT)
#define WS_DIST (WS_H + 2*HH*BB)
#define WS_BAR  (WS_DIST + BB*KCB)

#define LD_AG(p)   __hip_atomic_load((p), __ATOMIC_RELAXED, __HIP_MEMORY_SCOPE_AGENT)
#define ST_AG(p,v) __hip_atomic_store((p), (v), __ATOMIC_RELAXED, __HIP_MEMORY_SCOPE_AGENT)

__device__ __forceinline__ float sigf(float x){ return 1.0f/(1.0f+expf(-x)); }
__device__ __forceinline__ u16 bf16r(float f){ u32 u = __float_as_uint(f); u += 0x7FFFu + ((u>>16)&1u); return (u16)(u>>16); }
__device__ __forceinline__ float bf16f(u16 h){ return __uint_as_float(((u32)h)<<16); }

// ---- main (cross-XCD, L3) hierarchical barrier: proven rounds 5-10 ----
__device__ __forceinline__ void bar_arrive(u32* bar, int bid, int tid, int e){
    asm volatile("s_waitcnt vmcnt(0)" ::: "memory");   // my sc1 stores are at L3
    __syncthreads();
    if (tid == 0) {
        u32 old = atomicAdd(bar + (bid & 7) * 32, 1u);
        if (old == (u32)(e * 32 - 1)) {
            u32 old2 = atomicAdd(bar + 8 * 32, 1u);
            if (old2 == (u32)(e * 8 - 1)) {
                #pragma unroll
                for (int gg = 0; gg < 8; ++gg)
                    ST_AG(bar + (9 + gg) * 32, (u32)e);
            }
        }
    }
}
// acquire: spin, then agent-acquire fence (L1+L2 invalidate) -> plain loads fresh
__device__ __forceinline__ void bar_wait(u32* bar, int bid, int tid, int e){
    if (tid == 0) {
        while ((int)LD_AG(bar + (9 + (bid & 7)) * 32) < e)
            __builtin_amdgcn_s_sleep(1);
        __builtin_amdgcn_fence(__ATOMIC_ACQUIRE, "agent");
    }
    __syncthreads();
}

__global__ __launch_bounds__(512, 1)
void lstm_vq(const float* __restrict__ seq, const int* __restrict__ nit,
             const float* __restrict__ Wx, const float* __restrict__ Wh,
             const float* __restrict__ bias, const float* __restrict__ cb,
             float* __restrict__ out, float* __restrict__ ws)
{
    cg::grid_group grid = cg::this_grid();
    __shared__ __align__(16) u16 bHi[16*BPAD];   // 49408 B
    __shared__ __align__(16) u16 bLo[16*BPAD];   // 49408 B
    __shared__ float ex2[2][BB*16];              // 8192 B (two k-half planes)
    __shared__ int sBest;

    const int tid = threadIdx.x;
    const int l   = tid & 63;
    const int w   = tid >> 6;        // 0..7
    const int mt  = w >> 1;          // M-tile 0..3 (16 rows each)
    const int kh  = w & 1;           // k-half 0/1
    const int bid = (int)blockIdx.x;

    float* WT   = ws + WS_WT;
    u16*   hbuf = (u16*)(ws + WS_H);             // 2 bufs x 131072 u16
    float* dist = ws + WS_DIST;
    u32*   bar  = (u32*)(ws + WS_BAR);
    float* qz   = out + BB;
    float* uq   = out + BB + BB*HH;

    if (bid == 0 && tid < 17) ST_AG(bar + tid * 32, 0u);  // reset; ordered by grid.sync

    // ---------------- one-time: WT[zcol][k] = W[k][zcol] (512-thread version) ----------------
    {
        const int c0 = bid * 16;
        float* tile = (float*)bHi;               // 16 x 68 f32 scratch (pre-B-split)
        for (int kt = 0; kt < KTOT; kt += 64) {
            __syncthreads();
            #pragma unroll
            for (int ii2 = 0; ii2 < 2; ++ii2) {
                int ky = ii2*32 + (tid>>4);      // 0..63
                int cx = tid & 15;
                int kk = kt + ky;
                float v = (kk < II) ? Wx[(size_t)kk*GH + c0 + cx]
                                    : Wh[(size_t)(kk-II)*GH + c0 + cx];
                tile[cx*68 + ky] = v;
            }
            __syncthreads();
            {
                int cx = tid >> 5;               // 0..15
                int k2 = (tid & 31) * 2;         // 0..62
                WT[(size_t)(c0+cx)*KTOT + kt + k2]     = tile[cx*68 + k2];
                WT[(size_t)(c0+cx)*KTOT + kt + k2 + 1] = tile[cx*68 + k2 + 1];
            }
        }
        grid.sync();   // full fences: WT visible; orders barrier reset
    }

    // ---------------- one-time: split this block's 16 z-cols into bHi/bLo ----------------
    {
        __syncthreads();
        const int n  = tid >> 5;                              // 0..15
        const int zc = ((n>>2)<<10) + (bid<<2) + (n&3);
        const float* wr = WT + (size_t)zc*KTOT;
        for (int k = (tid&31)*8; k < KTOT; k += 256) {
            f32x4 v0 = *(const f32x4*)(wr + k);
            f32x4 v1 = *(const f32x4*)(wr + k + 4);
            short8 ph, pl;
            #pragma unroll
            for (int e = 0; e < 8; ++e) {
                float fv = (e<4) ? v0[e] : v1[e-4];
                u16 hb = bf16r(fv);
                ph[e] = (short)hb;
                pl[e] = (short)bf16r(fv - bf16f(hb));
            }
            *(short8*)&bHi[n*BPAD + k] = ph;
            *(short8*)&bLo[n*BPAD + k] = pl;
        }
        __syncthreads();
    }

    // ---------------- per-thread roles ----------------
    const int rEx  = (tid & 255) >> 2;           // gate phase (tid<256 only)
    const int ccEx = tid & 3;
    const int hcol = (bid<<2) + ccEx;
    const int myN  = nit[rEx];
    int maxN = 0;
    for (int i = 0; i < BB; ++i) maxN = max(maxN, nit[i]);

    const float bi_ = bias[hcol], bf_ = bias[HH+hcol], bg_ = bias[2*HH+hcol], bo_ = bias[3*HH+hcol];

    const int arow = (mt<<4) + (l&15);       // A row (batch row) this thread owns
    const int ag   = (l>>4)<<3;              // k sub-offset within K=32 slice
    const int bn   = l & 15;                 // B col this lane reads
    const int xkb  = kh << 8;                // x k-base for this wave (0/256)
    const int hkb  = kh << 9;                // h k-base (0/512)

    float cst = 0.0f;
    f32x4 xA0, xA1, xB0, xB1, xC0, xC1, xD0, xD1;    // x-phase 4-deep ring
    short8 p0h,p0l,p1h,p1l,p2h,p2l,p3h,p3l;          // h-phase 8-deep ring
    short8 p4h,p4l,p5h,p5l,p6h,p6l,p7h,p7l;

// ---- x phase: direct per-thread A loads + hi/lo split; wave covers 8 iters ----
#define XLD(buf, it) { \
    const float* xp_ = seq + (size_t)arow*(TT*II) + (size_t)t*II + xkb + ((it)<<5) + ag; \
    buf##0 = *(const f32x4*)xp_; buf##1 = *(const f32x4*)(xp_ + 4); }

#define XCOMP(buf, it) { \
    short8 ph, pl; \
    _Pragma("unroll") for (int e=0;e<8;++e){ \
        float fv = (e<4) ? buf##0[e] : buf##1[e-4]; \
        u16 hb = bf16r(fv); ph[e]=(short)hb; pl[e]=(short)bf16r(fv - bf16f(hb)); } \
    int bo = bn*BPAD + xkb + ((it)<<5) + ag; \
    short8 bhv = *(const short8*)&bHi[bo]; \
    short8 blv = *(const short8*)&bLo[bo]; \
    acc0 = __builtin_amdgcn_mfma_f32_16x16x32_bf16(ph, bhv, acc0, 0,0,0); \
    acc1 = __builtin_amdgcn_mfma_f32_16x16x32_bf16(pl, bhv, acc1, 0,0,0); \
    acc2 = __builtin_amdgcn_mfma_f32_16x16x32_bf16(ph, blv, acc2, 0,0,0); }

// ---- h phase: plane loads are DIRECT MFMA operands; wave covers 16 iters ----
#define HLD(B, it) { \
    const u16* hp_ = hiP + (size_t)arow*HH + hkb + ((it)<<5) + ag; \
    B##h = *(const short8*)hp_; \
    B##l = *(const short8*)(hp_ + 65536); }

#define HMFMA(B, it) { \
    int bo = bn*BPAD + 512 + hkb + ((it)<<5) + ag; \
    short8 bhv = *(const short8*)&bHi[bo]; \
    short8 blv = *(const short8*)&bLo[bo]; \
    acc0 = __builtin_amdgcn_mfma_f32_16x16x32_bf16(B##h, bhv, acc0, 0,0,0); \
    acc1 = __builtin_amdgcn_mfma_f32_16x16x32_bf16(B##l, bhv, acc1, 0,0,0); \
    acc2 = __builtin_amdgcn_mfma_f32_16x16x32_bf16(B##h, blv, acc2, 0,0,0); }

#define HSTEP(B, it) { HMFMA(B, it); if ((it) + 8 < 16) HLD(B, (it)+8); }

    for (int t = 0; t <= maxN; ++t) {
        const u16* hiP  = hbuf + (size_t)(t&1)*131072;       // hi plane; lo at +65536
        u16*       hiN  = hbuf + (size_t)(1-(t&1))*131072;
        u16*       loN  = hiN + 65536;

        f32x4 acc0 = {0.f,0.f,0.f,0.f};
        f32x4 acc1 = {0.f,0.f,0.f,0.f};
        f32x4 acc2 = {0.f,0.f,0.f,0.f};

        // ======== x GEMM (this wave: 256 k) — pre-wait, sync-free, 4-deep ring ========
        XLD(xA, 0); XLD(xB, 1); XLD(xC, 2); XLD(xD, 3);
        XCOMP(xA, 0); XLD(xA, 4);
        XCOMP(xB, 1); XLD(xB, 5);
        XCOMP(xC, 2); XLD(xC, 6);
        XCOMP(xD, 3); XLD(xD, 7);
        XCOMP(xA, 4); XCOMP(xB, 5); XCOMP(xC, 6); XCOMP(xD, 7);

        // ======== wait (spin + inv), then h GEMM (this wave: 512 k) — 8-deep ring ========
        if (t > 0) {
            bar_wait(bar, bid, tid, t);     // h(t-1) in L3; L1+L2 invalidated
            HLD(p0,0) HLD(p1,1) HLD(p2,2) HLD(p3,3)
            HLD(p4,4) HLD(p5,5) HLD(p6,6) HLD(p7,7)
            HSTEP(p0,0)  HSTEP(p1,1)  HSTEP(p2,2)  HSTEP(p3,3)
            HSTEP(p4,4)  HSTEP(p5,5)  HSTEP(p6,6)  HSTEP(p7,7)
            HSTEP(p0,8)  HSTEP(p1,9)  HSTEP(p2,10) HSTEP(p3,11)
            HSTEP(p4,12) HSTEP(p5,13) HSTEP(p6,14) HSTEP(p7,15)
        }

        // ---- exchange: each wave writes its k-half partial; gate threads sum both ----
        __syncthreads();
        {
            const int n  = l & 15;
            const int r0 = (mt<<4) + ((l>>4)<<2);
            #pragma unroll
            for (int j = 0; j < 4; ++j)
                ex2[kh][(r0+j)*16 + n] = acc0[j] + acc1[j] + acc2[j];
        }
        __syncthreads();
        if (tid < 256) {
            float zi = ex2[0][rEx*16 + 0*4 + ccEx] + ex2[1][rEx*16 + 0*4 + ccEx] + bi_;
            float zf = ex2[0][rEx*16 + 1*4 + ccEx] + ex2[1][rEx*16 + 1*4 + ccEx] + bf_;
            float zg = ex2[0][rEx*16 + 2*4 + ccEx] + ex2[1][rEx*16 + 2*4 + ccEx] + bg_;
            float zo = ex2[0][rEx*16 + 3*4 + ccEx] + ex2[1][rEx*16 + 3*4 + ccEx] + bo_;
            float iv = sigf(zi), fv = sigf(zf), gv = tanhf(zg), ov = sigf(zo);
            cst = fv*cst + iv*gv;
            float h = ov * tanhf(cst);
            u16 hb = bf16r(h);
            u16 lb = bf16r(h - bf16f(hb));
            ST_AG(&hiN[(size_t)rEx*HH + hcol], hb);
            ST_AG(&loN[(size_t)rEx*HH + hcol], lb);
            if (t == myN) ST_AG(&uq[(size_t)rEx*HH + hcol], h);
        }
        bar_arrive(bar, bid, tid, t + 1);
    }

    // ---------- VQ: distance^2 matrix [64][512] (2048 wave-slots x 16 pairs) ----------
    bar_wait(bar, bid, tid, maxN + 1);      // includes acquire fence -> plain reads OK
    {
        const int wid = bid*8 + w;
        for (int p = wid*16; p < wid*16 + 16; ++p) {
            int rr = p >> 9;
            int kk = p & 511;
            const u64* u8p = (const u64*)(uq + (size_t)rr*HH);
            const f32x4* c4 = (const f32x4*)(cb + (size_t)kk*HH);
            float s = 0.0f;
            #pragma unroll
            for (int q = 0; q < 4; ++q) {
                u64 e0 = u8p[2*(l + q*64)];
                u64 e1 = u8p[2*(l + q*64) + 1];
                f32x4 b = c4[l + q*64];
                float a0 = __uint_as_float((u32)e0), a1 = __uint_as_float((u32)(e0>>32));
                float a2 = __uint_as_float((u32)e1), a3 = __uint_as_float((u32)(e1>>32));
                float d0 = a0-b[0], d1 = a1-b[1], d2 = a2-b[2], d3 = a3-b[3];
                s += d0*d0 + d1*d1 + d2*d2 + d3*d3;
            }
            #pragma unroll
            for (int off = 32; off > 0; off >>= 1) s += __shfl_xor(s, off, 64);
            if (l == 0) ST_AG(&dist[(size_t)rr*KCB + kk], s);
        }
    }
    bar_arrive(bar, bid, tid, maxN + 2);
    bar_wait(bar, bid, tid, maxN + 2);      // fence -> plain dist reads OK

    // ---------- argmin + emit outputs (blocks 0..63, one row each) ----------
    if (bid < BB) {
        const int rr = bid;
        if (tid < 64) {
            float best = 3.4e38f;
            int   bi   = 0;
            for (int kk = tid; kk < KCB; kk += 64) {
                float v = dist[(size_t)rr*KCB + kk];
                if (v < best) { best = v; bi = kk; }
            }
            #pragma unroll
            for (int off = 32; off > 0; off >>= 1) {
                float ovv = __shfl_xor(best, off, 64);
                int   oii = __shfl_xor(bi,   off, 64);
                if (ovv < best || (ovv == best && oii < bi)) { best = ovv; bi = oii; }
            }
            if (tid == 0) { sBest = bi; out[rr] = (float)bi; }
        }
        __syncthreads();
        const int bk = sBest;
        const f32x4* c4 = (const f32x4*)(cb + (size_t)bk*HH);
        f32x4*       q4 = (f32x4*)(qz + (size_t)rr*HH);
        for (int d = tid; d < HH/4; d += 512) q4[d] = c4[d];
    }
}

extern "C" void kernel_launch(void* const* d_in, const int* in_sizes, int n_in,
                              void* d_out, int out_size, void* d_ws, size_t ws_size,
                              hipStream_t stream) {
    const float* seq  = (const float*)d_in[0];
    const int*   nit  = (const int*)  d_in[1];
    const float* Wx   = (const float*)d_in[2];
    const float* Wh   = (const float*)d_in[3];
    const float* bias = (const float*)d_in[4];
    const float* cb   = (const float*)d_in[5];
    float* out = (float*)d_out;
    float* ws  = (float*)d_ws;

    void* args[] = { &seq, &nit, &Wx, &Wh, &bias, &cb, &out, &ws };
    hipLaunchCooperativeKernel((void*)lstm_vq, dim3(256), dim3(512), args, 0, stream);
}